// Round 9
// baseline (480.347 us; speedup 1.0000x reference)
//
#include <hip/hip_runtime.h>

typedef unsigned short u16;
typedef unsigned int u32;
typedef __attribute__((ext_vector_type(8))) short bf8v;
typedef __attribute__((ext_vector_type(4))) float f4v;

#define RRELU_SLOPE 0.22916666667f

__device__ inline float bf2f(u16 u){ unsigned int i = ((unsigned int)u) << 16; float f; __builtin_memcpy(&f, &i, 4); return f; }
__device__ inline u16 f2bf(float f){ unsigned int i; __builtin_memcpy(&i, &f, 4); unsigned int r = (i + 0x7fffu + ((i >> 16) & 1u)) >> 16; return (u16)r; }
__device__ inline float frcp(float x){ return __builtin_amdgcn_rcpf(x); }
__device__ inline float fsigm(float x){ return frcp(1.f + __expf(-x)); }
__device__ inline float ftanh(float x){ return 2.f * frcp(1.f + __expf(-2.f * x)) - 1.f; }

// ---------------------------------------------------------------- prep: weight casts/transposes + ent cast + bias concat + edge histogram
__global__ __launch_bounds__(256) void prep_k(
    const float* __restrict__ Wn, const float* __restrict__ Wl, const float* __restrict__ We,
    const float* __restrict__ wih, const float* __restrict__ whh,
    const float* __restrict__ m1, const float* __restrict__ m2,
    const float* __restrict__ h1, const float* __restrict__ h2,
    const float* __restrict__ attn, const float* __restrict__ alg, const float* __restrict__ rel,
    const float* __restrict__ ent, const float* __restrict__ bat, const float* __restrict__ bh1,
    const int* __restrict__ edst, int E,
    u16* __restrict__ Bcat, u16* __restrict__ wihb, u16* __restrict__ whhb,
    u16* __restrict__ m1b, u16* __restrict__ m2b, u16* __restrict__ h1b, u16* __restrict__ h2b,
    u16* __restrict__ attnb, u16* __restrict__ algb, u16* __restrict__ relb,
    u16* __restrict__ entb, float* __restrict__ bias2, int* __restrict__ hist)
{
    int id = blockIdx.x * 256 + threadIdx.x;
    if (id < 49152) { // Bcat[n*384+k] : n in [0,128), k in [0,384)
        int n = id / 384, k = id % 384;
        float v = (k < 128) ? Wn[k*128 + n] : (k < 256 ? Wl[(k-128)*128 + n] : We[(k-256)*128 + n]);
        Bcat[id] = f2bf(v); return;
    }
    id -= 49152;
    if (id < 49152) { wihb[id] = f2bf(wih[id]); return; } id -= 49152;
    if (id < 49152) { whhb[id] = f2bf(whh[id]); return; } id -= 49152;
    if (id < 32768) { m1b[id]  = f2bf(m1[id]);  return; } id -= 32768;
    if (id < 32768) { m2b[id]  = f2bf(m2[id]);  return; } id -= 32768;
    if (id < 16384) { h1b[id]  = f2bf(h1[id]);  return; } id -= 16384;
    if (id < 16384) { h2b[id]  = f2bf(h2[id]);  return; } id -= 16384;
    if (id < 16384) { attnb[id]= f2bf(attn[id]);return; } id -= 16384;
    if (id < 16384) { algb[id] = f2bf(alg[id]); return; } id -= 16384;
    if (id < 58880) { relb[id] = f2bf(rel[id]); return; } id -= 58880;
    if (id < 2560000) { entb[id] = f2bf(ent[id]); return; } id -= 2560000;
    if (id < 256) { bias2[id] = (id < 128) ? bat[id] : bh1[id - 128]; return; } id -= 256;
    if (id < E) atomicAdd(&hist[edst[id]], 1);
}

// ---------------------------------------------------------------- exclusive scan over 20000 bins (1 block)
__global__ __launch_bounds__(1024) void scan_k(
    const int* __restrict__ hist, int* __restrict__ starts, int* __restrict__ cursor)
{
    __shared__ int part[1024];
    int t = threadIdx.x;
    int base = t * 20;
    int s = 0;
    for (int j = 0; j < 20; ++j) { int idx = base + j; if (idx < 20000) s += hist[idx]; }
    part[t] = s;
    __syncthreads();
    for (int off = 1; off < 1024; off <<= 1) {
        int v = (t >= off) ? part[t - off] : 0;
        __syncthreads();
        part[t] += v;
        __syncthreads();
    }
    int run = (t > 0) ? part[t - 1] : 0;
    for (int j = 0; j < 20; ++j) {
        int idx = base + j;
        if (idx < 20000) { starts[idx] = run; cursor[idx] = run; run += hist[idx]; }
    }
    if (t == 1023) starts[20000] = run;
}

// ---------------------------------------------------------------- co-dispatch: scatter edges (blocks < eb) | fused 2-layer rel map (8 blocks)
__global__ __launch_bounds__(256) void scmap_k(
    const int* __restrict__ src, const int* __restrict__ dst, const int* __restrict__ typ,
    int* __restrict__ cursor, int2* __restrict__ spack, int E, int eb,
    const u16* __restrict__ relb, const u16* __restrict__ m1b, const float* __restrict__ bm1,
    const u16* __restrict__ m2b, const float* __restrict__ bm2,
    u16* __restrict__ mapb, u16* __restrict__ mapT)
{
    __shared__ u16 t1l[4][16][264];
    int tid = threadIdx.x;
    if ((int)blockIdx.x < eb) {
        int e = blockIdx.x * 256 + tid;
        if (e >= E) return;
        int d = dst[e];
        int p = atomicAdd(&cursor[d], 1);
        spack[p] = make_int2(src[e], typ[e]);
        return;
    }
    // ---- fused rel map: rel -> t1(256) -> mapped_rel(128) (+ mapT)
    int wave = tid >> 6, lane = tid & 63;
    int ln = lane & 15, q = lane >> 4;
    int base = (blockIdx.x - eb) * 64 + wave * 16;
    int arow = base + ln; if (arow > 459) arow = 459;
    const u16* Ap = relb + arow * 128;
    f4v acc1[16] = {};
    for (int kc = 0; kc < 128; kc += 32) {
        bf8v af = *(const bf8v*)(Ap + kc + q*8);
#pragma unroll
        for (int nt = 0; nt < 16; ++nt) {
            bf8v bv = *(const bf8v*)(m1b + (nt*16 + ln)*128 + kc + q*8);
            acc1[nt] = __builtin_amdgcn_mfma_f32_16x16x32_bf16(af, bv, acc1[nt], 0, 0, 0);
        }
    }
#pragma unroll
    for (int nt = 0; nt < 16; ++nt) {
        int n = nt*16 + ln;
        float bv = bm1[n];
#pragma unroll
        for (int r = 0; r < 4; ++r)
            t1l[wave][q*4 + r][n] = f2bf(acc1[nt][r] + bv);
    }
    // wave-private staging: no block barrier needed
    f4v acc2[8] = {};
    for (int kc = 0; kc < 256; kc += 32) {
        bf8v af = *(const bf8v*)&t1l[wave][ln][kc + q*8];
#pragma unroll
        for (int nt = 0; nt < 8; ++nt) {
            bf8v bv = *(const bf8v*)(m2b + (nt*16 + ln)*256 + kc + q*8);
            acc2[nt] = __builtin_amdgcn_mfma_f32_16x16x32_bf16(af, bv, acc2[nt], 0, 0, 0);
        }
    }
#pragma unroll
    for (int nt = 0; nt < 8; ++nt) {
        int n = nt*16 + ln;
        float bv = bm2[n];
#pragma unroll
        for (int r = 0; r < 4; ++r) {
            int m = base + q*4 + r;
            if (m < 460) {
                u16 hv = f2bf(acc2[nt][r] + bv);
                mapb[m*128 + n] = hv;
                mapT[n*480 + m] = hv;
            }
        }
    }
}

// ---------------------------------------------------------------- co-dispatch: [agg + pre_emb + aligned fused, 5000 blocks x 4 entities,
//                                           ONE WAVE PER ENTITY]  | [q_rel gather -> attnq|th1 -> pred, 16 blocks]
__global__ __launch_bounds__(256) void aggpq_k(
    const int2* __restrict__ spack, const int* __restrict__ starts,
    const u32* __restrict__ hb, const u32* __restrict__ rb,
    const u16* __restrict__ bcat, const u16* __restrict__ alb, const float* __restrict__ bal,
    u16* __restrict__ preb, u16* __restrict__ alnb,
    const u16* __restrict__ mapb, const int* __restrict__ trip,
    const u16* __restrict__ atb, const float* __restrict__ bias2,
    const u16* __restrict__ h2b, const float* __restrict__ bh2,
    u16* __restrict__ atq, float* __restrict__ pred, u16* __restrict__ X)
{
    __shared__ u16 acatl[4][392];     // 4 entity rows x 384 (+8 pad)
    __shared__ u16 prel[4][136];
    __shared__ u16 th1l[4][16][136];
    int tid = threadIdx.x;
    int wave = tid >> 6, lane = tid & 63;
    int ln = lane & 15, q = lane >> 4;
    if (blockIdx.x < 5000) {
        int e0 = blockIdx.x * 4;
        // gather: one wave per entity (restores 20000-wave TLP; accumulation order identical)
        {
            int i = e0 + wave;
            int s0 = starts[i], s1 = starts[i + 1];
            float sx = 0.f, sy = 0.f;
            int e = s0;
            for (; e + 4 <= s1; e += 4) {
                int2 st0 = spack[e], st1 = spack[e+1], st2 = spack[e+2], st3 = spack[e+3];
                u32 a0 = hb[(long)st0.x * 64 + lane]; u32 r0 = rb[(long)st0.y * 64 + lane];
                u32 a1 = hb[(long)st1.x * 64 + lane]; u32 r1 = rb[(long)st1.y * 64 + lane];
                u32 a2 = hb[(long)st2.x * 64 + lane]; u32 r2 = rb[(long)st2.y * 64 + lane];
                u32 a3 = hb[(long)st3.x * 64 + lane]; u32 r3 = rb[(long)st3.y * 64 + lane];
                sx += bf2f((u16)(a0 & 0xffff)) + bf2f((u16)(r0 & 0xffff));
                sy += bf2f((u16)(a0 >> 16))    + bf2f((u16)(r0 >> 16));
                sx += bf2f((u16)(a1 & 0xffff)) + bf2f((u16)(r1 & 0xffff));
                sy += bf2f((u16)(a1 >> 16))    + bf2f((u16)(r1 >> 16));
                sx += bf2f((u16)(a2 & 0xffff)) + bf2f((u16)(r2 & 0xffff));
                sy += bf2f((u16)(a2 >> 16))    + bf2f((u16)(r2 >> 16));
                sx += bf2f((u16)(a3 & 0xffff)) + bf2f((u16)(r3 & 0xffff));
                sy += bf2f((u16)(a3 >> 16))    + bf2f((u16)(r3 >> 16));
            }
            for (; e < s1; ++e) {
                int2 st = spack[e];
                u32 a = hb[(long)st.x * 64 + lane];
                u32 r = rb[(long)st.y * 64 + lane];
                sx += bf2f((u16)(a & 0xffff)) + bf2f((u16)(r & 0xffff));
                sy += bf2f((u16)(a >> 16))    + bf2f((u16)(r >> 16));
            }
            bool has = s1 > s0;
            float nrm = has ? frcp((float)(s1 - s0)) : 0.f;
            u32 hv = hb[(long)i * 64 + lane];
            u32 agg = (u32)f2bf(sx * nrm) | ((u32)f2bf(sy * nrm) << 16);
            u32* row = (u32*)&acatl[wave][0];
            row[lane]       = agg;
            row[64 + lane]  = has ? hv : 0u;
            row[128 + lane] = has ? 0u : hv;
        }
        __syncthreads();
        // stage 1: pre = rrelu(acat @ Bcat^T); replicated A-rows (ln&3), each wave 32 cols.
        // MFMA C rows 0..3 (lanes q==0) hold the 4 entities.
        f4v acc[2] = {};
        for (int kc = 0; kc < 384; kc += 32) {
            bf8v af = *(const bf8v*)&acatl[ln & 3][kc + q*8];
#pragma unroll
            for (int t = 0; t < 2; ++t) {
                bf8v bv = *(const bf8v*)(bcat + (wave*32 + t*16 + ln)*384 + kc + q*8);
                acc[t] = __builtin_amdgcn_mfma_f32_16x16x32_bf16(af, bv, acc[t], 0, 0, 0);
            }
        }
        if (q == 0) {
#pragma unroll
            for (int t = 0; t < 2; ++t) {
                int n = wave*32 + t*16 + ln;
#pragma unroll
                for (int r = 0; r < 4; ++r) {
                    float v = acc[t][r];
                    v = (v >= 0.f) ? v : v * RRELU_SLOPE;
                    u16 hv2 = f2bf(v);
                    prel[r][n] = hv2;
                    preb[(long)(e0 + r)*128 + n] = hv2;
                }
            }
        }
        __syncthreads();
        // stage 2: aligned = pre @ W_align^T + b  (same replicated-row pattern)
        f4v acc2[2] = {};
        for (int kc = 0; kc < 128; kc += 32) {
            bf8v af = *(const bf8v*)&prel[ln & 3][kc + q*8];
#pragma unroll
            for (int t = 0; t < 2; ++t) {
                bf8v bv = *(const bf8v*)(alb + (wave*32 + t*16 + ln)*128 + kc + q*8);
                acc2[t] = __builtin_amdgcn_mfma_f32_16x16x32_bf16(af, bv, acc2[t], 0, 0, 0);
            }
        }
        if (q == 0) {
#pragma unroll
            for (int t = 0; t < 2; ++t) {
                int n = wave*32 + t*16 + ln;
                float bv = bal[n];
#pragma unroll
                for (int r = 0; r < 4; ++r)
                    alnb[(long)(e0 + r)*128 + n] = f2bf(acc2[t][r] + bv);
            }
        }
        return;
    }
    // ---- fuse_qt branch: q_rel gather -> [attnq | th1] -> pred (+ X tail rows)
    int base = (blockIdx.x - 5000) * 64 + wave * 16;
    int ar = trip[(base + ln)*3 + 1];
    const u16* Ap = mapb + ar * 128;
    int rm_[4];
#pragma unroll
    for (int r = 0; r < 4; ++r) rm_[r] = trip[(base + q*4 + r)*3 + 1];
    f4v acc1[16] = {};
    for (int kc = 0; kc < 128; kc += 32) {
        bf8v af = *(const bf8v*)(Ap + kc + q*8);
#pragma unroll
        for (int nt = 0; nt < 16; ++nt) {
            bf8v bv = *(const bf8v*)(atb + (nt*16 + ln)*128 + kc + q*8);
            acc1[nt] = __builtin_amdgcn_mfma_f32_16x16x32_bf16(af, bv, acc1[nt], 0, 0, 0);
        }
    }
#pragma unroll
    for (int nt = 0; nt < 16; ++nt) {
        int n = nt*16 + ln;
        float bv = bias2[n];
#pragma unroll
        for (int r = 0; r < 4; ++r) {
            int m = base + q*4 + r;
            float x = acc1[nt][r] + bv;
            if (nt < 8) {
                atq[m*128 + n] = f2bf(x);
                X[(long)(8192 + m)*128 + n] = mapb[rm_[r]*128 + n];  // X tail = q_rel
            } else th1l[wave][q*4 + r][n - 128] = f2bf(x);
        }
    }
    // wave-private staging: no block barrier needed
    f4v acc2[8] = {};
    for (int kc = 0; kc < 128; kc += 32) {
        bf8v af = *(const bf8v*)&th1l[wave][ln][kc + q*8];
#pragma unroll
        for (int nt = 0; nt < 8; ++nt) {
            bf8v bv = *(const bf8v*)(h2b + (nt*16 + ln)*128 + kc + q*8);
            acc2[nt] = __builtin_amdgcn_mfma_f32_16x16x32_bf16(af, bv, acc2[nt], 0, 0, 0);
        }
    }
#pragma unroll
    for (int nt = 0; nt < 8; ++nt) {
        int n = nt*16 + ln;
        float bv = bh2[n];
#pragma unroll
        for (int r = 0; r < 4; ++r) {
            int m = base + q*4 + r;
            pred[(long)m*128 + n] = 0.1f * (acc2[nt][r] + bv) + bf2f(mapb[rm_[r]*128 + n]);
        }
    }
}

// ---------------------------------------------------------------- fused A-rows + masked-softmax(460) + rel_path GEMM (K=480)
// block = 4 batch rows x 8 timesteps; A rows computed in-kernel via replicated-row MFMA
__global__ __launch_bounds__(256) void smrp_k(
    const u16* __restrict__ atq, const u16* __restrict__ mapb,
    const float* __restrict__ part, const u16* __restrict__ mapT, u16* __restrict__ X)
{
    __shared__ u16 xls[32][488];
    __shared__ float asl[4][464];
    int tid = threadIdx.x;
    int wave = tid >> 6, lane = tid & 63;
    int ln = lane & 15, q = lane >> 4;
    int b0 = blockIdx.x * 4;           // 256 blocks x 4 batch rows
    // A[db][n] = atq[b0+db] @ mapped_rel^T  (29 n-tiles strided over waves)
    {
        const u16* Ap = atq + (long)(b0 + (ln & 3)) * 128;
        bf8v af[4];
#pragma unroll
        for (int kc = 0; kc < 4; ++kc) af[kc] = *(const bf8v*)(Ap + kc*32 + q*8);
        for (int nt = wave; nt < 29; nt += 4) {
            int brow = nt*16 + ln; if (brow > 459) brow = 459;
            f4v acc = {};
#pragma unroll
            for (int kc = 0; kc < 4; ++kc) {
                bf8v bv = *(const bf8v*)(mapb + (long)brow*128 + kc*32 + q*8);
                acc = __builtin_amdgcn_mfma_f32_16x16x32_bf16(af[kc], bv, acc, 0, 0, 0);
            }
            if (q == 0) {
                int n = nt*16 + ln;
                if (n < 460) {
#pragma unroll
                    for (int r = 0; r < 4; ++r) asl[r][n] = acc[r];
                }
            }
        }
    }
    __syncthreads();
    for (int j = 0; j < 8; ++j) {
        int rl = wave*8 + j;           // rl = t*4 + db
        int t = rl >> 2, db = rl & 3;
        const float* crow = part + (long)(b0 + db)*3680 + t*460;
        float v[8], e[8];
        float m = -1e30f;
#pragma unroll
        for (int i = 0; i < 8; ++i) {
            int r = i*64 + lane;
            if (r < 460) {
                float x = crow[r] * asl[db][r];
                x = (x == 0.f) ? -1e9f : x;
                v[i] = x; m = fmaxf(m, x);
            } else v[i] = -1e30f;
        }
#pragma unroll
        for (int off = 32; off; off >>= 1) m = fmaxf(m, __shfl_xor(m, off));
        float sum = 0.f;
#pragma unroll
        for (int i = 0; i < 8; ++i) {
            int r = i*64 + lane;
            e[i] = 0.f;
            if (r < 460) { e[i] = __expf(v[i] - m); sum += e[i]; }
        }
#pragma unroll
        for (int off = 32; off; off >>= 1) sum += __shfl_xor(sum, off);
        float inv = frcp(sum);
#pragma unroll
        for (int i = 0; i < 8; ++i) {
            int r = i*64 + lane;
            if (r < 460)      xls[rl][r] = f2bf(e[i] * inv);
            else if (r < 488) xls[rl][r] = 0;
        }
    }
    __syncthreads();
    f4v acc[2][2] = {};
    for (int kc = 0; kc < 480; kc += 32) {
        bf8v a[2], bfr[2];
#pragma unroll
        for (int mt = 0; mt < 2; ++mt)
            a[mt] = *(const bf8v*)&xls[mt*16 + ln][kc + q*8];
#pragma unroll
        for (int nt = 0; nt < 2; ++nt)
            bfr[nt] = *(const bf8v*)(mapT + (wave*32 + nt*16 + ln)*480 + kc + q*8);
#pragma unroll
        for (int mt = 0; mt < 2; ++mt)
#pragma unroll
            for (int nt = 0; nt < 2; ++nt)
                acc[mt][nt] = __builtin_amdgcn_mfma_f32_16x16x32_bf16(a[mt], bfr[nt], acc[mt][nt], 0, 0, 0);
    }
#pragma unroll
    for (int mt = 0; mt < 2; ++mt)
#pragma unroll
    for (int nt = 0; nt < 2; ++nt) {
        int n = wave*32 + nt*16 + ln;
#pragma unroll
        for (int r = 0; r < 4; ++r) {
            int rl = mt*16 + q*4 + r;
            long m = (long)(rl >> 2)*1024 + b0 + (rl & 3);
            X[m*128 + n] = f2bf(acc[mt][nt][r]);
        }
    }
}

// ---------------------------------------------------------------- GRU scan: fused gi = X@wih^T, fused SubL prologue, fused V/obj epilogue
__global__ __launch_bounds__(256, 1) void gru_k(
    const u16* __restrict__ X, const u16* __restrict__ wihb, const float* __restrict__ bih,
    const u16* __restrict__ whhb, const float* __restrict__ bhh,
    const float* __restrict__ pred,
    const u16* __restrict__ preb, const u16* __restrict__ alb, const float* __restrict__ bal,
    const u16* __restrict__ AL, const int* __restrict__ trip,
    u16* __restrict__ V, float* __restrict__ accp)
{
    __shared__ u16  hbf[16][136];   // rows 4..15 stay zero
    __shared__ float hf [4][128];
    __shared__ float ghl[4][388];
    __shared__ float gil[4][388];
    __shared__ float sll[4][132];
    __shared__ float redm[4], redo[4];
    int tid = threadIdx.x;
    int wave = tid >> 6, lane = tid & 63;
    int ln = lane & 15, q = lane >> 4;
    int bb = blockIdx.x * 4;
    for (int i = tid; i < 16*136; i += 256) hbf[i/136][i%136] = 0;
    for (int i = tid; i < 4*128; i += 256) hf[i>>7][i&127] = 0.f;
    // preload whh + wih fragments: 6 N-tiles x 4 K-chunks per wave each (192 VGPRs; 1 blk/CU anyway)
    bf8v bfrag[6][4], wfrag[6][4];
#pragma unroll
    for (int nt = 0; nt < 6; ++nt)
#pragma unroll
        for (int kc = 0; kc < 4; ++kc) {
            bfrag[nt][kc] = *(const bf8v*)(whhb + (long)(wave*96 + nt*16 + ln)*128 + kc*32 + q*8);
            wfrag[nt][kc] = *(const bf8v*)(wihb + (long)(wave*96 + nt*16 + ln)*128 + kc*32 + q*8);
        }
    // SubL = pre_emb[trip[:,0]] @ W_align^T + b_align for this block's 4 rows
    {
        const u16* Pp = preb + (long)trip[(bb + (ln & 3))*3 + 0] * 128;
        f4v sacc[2] = {};
#pragma unroll
        for (int kc = 0; kc < 4; ++kc) {
            bf8v pf = *(const bf8v*)(Pp + kc*32 + q*8);
#pragma unroll
            for (int nt = 0; nt < 2; ++nt) {
                bf8v bv = *(const bf8v*)(alb + (long)(wave*32 + nt*16 + ln)*128 + kc*32 + q*8);
                sacc[nt] = __builtin_amdgcn_mfma_f32_16x16x32_bf16(pf, bv, sacc[nt], 0, 0, 0);
            }
        }
        if (q == 0) {
#pragma unroll
            for (int nt = 0; nt < 2; ++nt) {
                int n = wave*32 + nt*16 + ln;
                float bv = bal[n];
#pragma unroll
                for (int r = 0; r < 4; ++r) sll[r][n] = sacc[nt][r] + bv;
            }
        }
    }
    int k = tid & 127;
    float cr = bih[k] + bhh[k];
    float cz = bih[128 + k] + bhh[128 + k];
    float bin_ = bih[256 + k], bhn = bhh[256 + k];
    __syncthreads();
    float msum = 0.f, osum = 0.f;
    for (int t = 0; t <= 8; ++t) {
        float pv[2];
#pragma unroll
        for (int it = 0; it < 2; ++it) {
            int m = it*2 + (tid >> 7);
            pv[it] = (t >= 7) ? pred[(long)(bb + m)*128 + k] : 0.f;
        }
        if (t == 8) {
#pragma unroll
            for (int it = 0; it < 2; ++it) {
                int m = it*2 + (tid >> 7);
                hf[m][k] = pv[it]; hbf[m][k] = f2bf(pv[it]);
            }
            __syncthreads();
        }
        // gi = x_t @ wih^T (rows from X, 4-way replicated across lanes) ; gh = h @ whh^T
        long xr0 = (t < 8) ? ((long)t*1024 + bb) : (long)(8192 + bb);
        const u16* Xp = X + (xr0 + (ln & 3))*128;
        f4v gacc[6] = {};
        f4v acc[6] = {};
#pragma unroll
        for (int kc = 0; kc < 4; ++kc) {
            bf8v xf = *(const bf8v*)(Xp + kc*32 + q*8);
            bf8v af = *(const bf8v*)&hbf[ln][kc*32 + q*8];
#pragma unroll
            for (int nt = 0; nt < 6; ++nt) {
                gacc[nt] = __builtin_amdgcn_mfma_f32_16x16x32_bf16(xf, wfrag[nt][kc], gacc[nt], 0, 0, 0);
                acc[nt]  = __builtin_amdgcn_mfma_f32_16x16x32_bf16(af, bfrag[nt][kc], acc[nt],  0, 0, 0);
            }
        }
        if (q == 0) {
#pragma unroll
            for (int nt = 0; nt < 6; ++nt)
#pragma unroll
                for (int r = 0; r < 4; ++r) {
                    ghl[r][wave*96 + nt*16 + ln] = acc[nt][r];
                    gil[r][wave*96 + nt*16 + ln] = gacc[nt][r];
                }
        }
        __syncthreads();
#pragma unroll
        for (int it = 0; it < 2; ++it) {
            int m = it*2 + (tid >> 7);
            float rr = fsigm(gil[m][k] + ghl[m][k] + cr);
            float zz = fsigm(gil[m][128 + k] + ghl[m][128 + k] + cz);
            float nn = ftanh(gil[m][256 + k] + bin_ + rr * (ghl[m][256 + k] + bhn));
            float hn = (1.f - zz) * nn + zz * hf[m][k];
            if (t == 7) { float d = pv[it] - hn; msum += d*d; }
            if (t == 8) {
                u16 vb = f2bf(sll[m][k] * hn);
                V[(long)(bb + m)*128 + k] = vb;
                int obj = trip[(bb + m)*3 + 2];
                osum += bf2f(vb) * bf2f(AL[(long)obj*128 + k]);
            } else { hf[m][k] = hn; hbf[m][k] = f2bf(hn); }
        }
        __syncthreads();
    }
#pragma unroll
    for (int off = 32; off; off >>= 1) { msum += __shfl_down(msum, off); osum += __shfl_down(osum, off); }
    if (lane == 0) { redm[wave] = msum; redo[wave] = osum; }
    __syncthreads();
    if (tid == 0) {
        atomicAdd(accp + 0, redm[0] + redm[1] + redm[2] + redm[3]);
        atomicAdd(accp + 2, -(redo[0] + redo[1] + redo[2] + redo[3]));
    }
}

// ---------------------------------------------------------------- score GEMM: 8 waves x (64x32)/wave, half-tile LDS staging,
// full-line nt stores; grid (8,157): consecutive blocks share the AL column strip for L2 reuse.
// e = exp(-|s|), d = 1+e:  sigma = (s>=0 ? 1 : e)/d ;  softplus(s) = max(s,0) + log(d)
__global__ __launch_bounds__(512) void score_k(
    const u16* __restrict__ V, const u16* __restrict__ AL,
    float* __restrict__ out, float* __restrict__ sp_acc, int N)
{
    __shared__ float stage[8][1024];   // 32 rows x 32 cols f32 per wave (wave-private)
    int tid = threadIdx.x;
    int wave = tid >> 6, lane = tid & 63;
    int ln = lane & 15, q = lane >> 4;
    int bm = blockIdx.x * 128 + (wave >> 2) * 64;
    int bn = blockIdx.y * 128 + (wave & 3) * 32;
    bool valid = bn < N;               // N % 32 == 0 -> whole 32-col strip valid or not
    int br[2];
#pragma unroll
    for (int nt = 0; nt < 2; ++nt) { int n = bn + nt*16 + ln; br[nt] = (n < N) ? n : (N - 1); }
    f4v acc[4][2] = {};
    for (int kc = 0; kc < 128; kc += 32) {
        bf8v a[4], b[2];
#pragma unroll
        for (int mt = 0; mt < 4; ++mt)
            a[mt] = *(const bf8v*)(V + (long)(bm + mt*16 + ln)*128 + kc + q*8);
#pragma unroll
        for (int nt = 0; nt < 2; ++nt)
            b[nt] = *(const bf8v*)(AL + (long)br[nt]*128 + kc + q*8);
#pragma unroll
        for (int mt = 0; mt < 4; ++mt)
#pragma unroll
            for (int nt = 0; nt < 2; ++nt)
                acc[mt][nt] = __builtin_amdgcn_mfma_f32_16x16x32_bf16(a[mt], b[nt], acc[mt][nt], 0, 0, 0);
    }
    float lsum = 0.f;
    float* st = stage[wave];
#pragma unroll
    for (int half = 0; half < 2; ++half) {
#pragma unroll
        for (int mh = 0; mh < 2; ++mh) {
            int mt = half*2 + mh;
#pragma unroll
            for (int nt = 0; nt < 2; ++nt)
#pragma unroll
            for (int r = 0; r < 4; ++r) {
                float s = acc[mt][nt][r];
                float e = __expf(-fabsf(s));
                float d = 1.f + e;
                float inv = frcp(d);
                st[(mh*16 + q*4 + r)*32 + nt*16 + ln] = (s >= 0.f) ? inv : e * inv;
                lsum += fmaxf(s, 0.f) + __logf(d);
            }
        }
        // wave-private LDS: no block barrier needed; write full 128B lines
        if (valid) {
            int row0 = lane >> 3, c4 = (lane & 7) << 2;
#pragma unroll
            for (int i = 0; i < 4; ++i) {
                int row = i*8 + row0;
                f4v vv = *(const f4v*)&st[row*32 + c4];
                __builtin_nontemporal_store(vv, (f4v*)&out[(long)(bm + half*32 + row)*N + bn + c4]);
            }
        }
    }
    if (!valid) lsum = 0.f;
#pragma unroll
    for (int off = 32; off; off >>= 1) lsum += __shfl_xor(lsum, off);
    __shared__ float red[8];
    if (lane == 0) red[wave] = lsum;
    __syncthreads();
    if (tid == 0) {
        float tsum = 0.f;
#pragma unroll
        for (int w = 0; w < 8; ++w) tsum += red[w];
        atomicAdd(sp_acc, tsum);
    }
}

// ---------------------------------------------------------------- finalize scalars
__global__ void final_k(const float* __restrict__ acc, float* __restrict__ out)
{
    out[20480000] = acc[0] / (1024.f * 128.f);
    out[20480001] = (acc[1] + acc[2]) / (1024.f * 20000.f);
}

// ================================================================ host
extern "C" void kernel_launch(void* const* d_in, const int* in_sizes, int n_in,
                              void* d_out, int out_size, void* d_ws, size_t ws_size,
                              hipStream_t stream)
{
    const float* ent  = (const float*)d_in[0];
    const float* rel  = (const float*)d_in[1];
    const float* Wn   = (const float*)d_in[2];
    const float* Wl   = (const float*)d_in[3];
    const float* We   = (const float*)d_in[4];
    const float* wih  = (const float*)d_in[5];
    const float* whh  = (const float*)d_in[6];
    const float* b_ih = (const float*)d_in[7];
    const float* b_hh = (const float*)d_in[8];
    const float* Wm1  = (const float*)d_in[9];
    const float* bm1  = (const float*)d_in[10];
    const float* Wm2  = (const float*)d_in[11];
    const float* bm2  = (const float*)d_in[12];
    const float* Wh1  = (const float*)d_in[13];
    const float* bh1  = (const float*)d_in[14];
    const float* Wh2  = (const float*)d_in[15];
    const float* bh2  = (const float*)d_in[16];
    const float* Wal  = (const float*)d_in[17];
    const float* bal  = (const float*)d_in[18];
    const float* Wat  = (const float*)d_in[19];
    const float* bat  = (const float*)d_in[20];
    const float* part = (const float*)d_in[21];
    const int* esrc   = (const int*)d_in[22];
    const int* edst   = (const int*)d_in[23];
    const int* etyp   = (const int*)d_in[24];
    const int* trip   = (const int*)d_in[25];
    float* out = (float*)d_out;
    const int E = in_sizes[22];

    char* ws = (char*)d_ws;
    size_t off = 0;
    auto alloc = [&](size_t bytes) { size_t o = off; off = (off + bytes + 255) & ~(size_t)255; return o; };

    // zeroed region first (one memset)
    size_t o_acc   = alloc(256);                  // [0]=match [1]=softplus [2]=obj
    size_t o_hist  = alloc(20000 * 4);
    size_t o_mapT  = alloc(128 * 480 * 2);
    size_t zend = off;
    // non-zeroed
    size_t o_starts= alloc(20004 * 4);
    size_t o_cur   = alloc(20000 * 4);
    size_t o_spack = alloc((size_t)E * 8);
    size_t o_entb  = alloc((size_t)20000 * 128 * 2);
    size_t o_pre   = alloc((size_t)20000 * 128 * 2);
    size_t o_aln   = alloc((size_t)20000 * 128 * 2);
    size_t o_bcat  = alloc(128 * 384 * 2);
    size_t o_wih   = alloc(384 * 128 * 2);
    size_t o_whh   = alloc(384 * 128 * 2);
    size_t o_m1    = alloc(256 * 128 * 2);
    size_t o_m2    = alloc(128 * 256 * 2);
    size_t o_ath   = alloc(2 * 128 * 128 * 2);    // [W_attn ; W_h1] adjacent (N=256 stage-1)
    size_t o_h2    = alloc(128 * 128 * 2);
    size_t o_al    = alloc(128 * 128 * 2);
    size_t o_rel   = alloc(460 * 128 * 2);
    size_t o_map   = alloc(460 * 128 * 2);
    size_t o_atq   = alloc(1024 * 128 * 2);
    size_t o_b2    = alloc(256 * 4);              // [b_attn ; b_h1]
    size_t o_pred  = alloc(1024 * 128 * 4);
    size_t o_X     = alloc((size_t)9216 * 128 * 2);
    size_t o_V     = alloc(1024 * 128 * 2);

    float* accp  = (float*)(ws + o_acc);
    int* histp   = (int*)(ws + o_hist);
    u16* mapT    = (u16*)(ws + o_mapT);
    int* startsp = (int*)(ws + o_starts);
    int* curp    = (int*)(ws + o_cur);
    int2* spack  = (int2*)(ws + o_spack);
    u16* entb    = (u16*)(ws + o_entb);
    u16* preb    = (u16*)(ws + o_pre);
    u16* alnb    = (u16*)(ws + o_aln);
    u16* bcat    = (u16*)(ws + o_bcat);
    u16* wihb    = (u16*)(ws + o_wih);
    u16* whhb    = (u16*)(ws + o_whh);
    u16* m1b     = (u16*)(ws + o_m1);
    u16* m2b     = (u16*)(ws + o_m2);
    u16* atb     = (u16*)(ws + o_ath);
    u16* h1b     = atb + 128 * 128;
    u16* h2b     = (u16*)(ws + o_h2);
    u16* alb     = (u16*)(ws + o_al);
    u16* relb    = (u16*)(ws + o_rel);
    u16* mapb    = (u16*)(ws + o_map);
    u16* atqb    = (u16*)(ws + o_atq);
    float* bias2 = (float*)(ws + o_b2);
    float* predf = (float*)(ws + o_pred);
    u16* Xb      = (u16*)(ws + o_X);
    u16* Vb      = (u16*)(ws + o_V);

    hipMemsetAsync(ws, 0, zend, stream);

    // prep covers: weights (337408) + ent cast (2560000) + bias concat (256) + edge histogram (E)
    int ptot = 2897664 + E;
    prep_k<<<(ptot + 255) / 256, 256, 0, stream>>>(
        Wn, Wl, We, wih, whh, Wm1, Wm2, Wh1, Wh2, Wat, Wal, rel,
        ent, bat, bh1, edst, E,
        bcat, wihb, whhb, m1b, m2b, h1b, h2b, atb, alb, relb,
        entb, bias2, histp);

    scan_k<<<1, 1024, 0, stream>>>(histp, startsp, curp);

    // co-dispatch: scatter (eb blocks) | rel-map (8 blocks)
    int eb = (E + 255) / 256;
    scmap_k<<<eb + 8, 256, 0, stream>>>(esrc, edst, etyp, curp, spack, E, eb,
                                        relb, m1b, bm1, m2b, bm2, mapb, mapT);

    // co-dispatch: agg+pre+aligned fused (5000 blocks, 1 wave/entity) | q_rel->attnq/th1->pred (16 blocks)
    aggpq_k<<<5016, 256, 0, stream>>>(spack, startsp, (const u32*)entb, (const u32*)relb,
                                      bcat, alb, bal, preb, alnb,
                                      mapb, trip, atb, bias2, h2b, bh2, atqb, predf, Xb);

    // A-rows + softmax + rel_path fused -> X rows 0..8191 (bf16)
    smrp_k<<<256, 256, 0, stream>>>(atqb, mapb, part, mapT, Xb);

    // GRU scan with fused gi-GEMM, SubL prologue, V/obj epilogue
    gru_k<<<256, 256, 0, stream>>>(Xb, wihb, b_ih, whhb, b_hh, predf, preb, alb, bal, alnb, trip, Vb, accp);

    // score + softplus reduce  (grid: row-tiles fastest -> AL strip L2 reuse)
    score_k<<<dim3(8, 157), 512, 0, stream>>>(Vb, alnb, out, accp + 1, 20000);

    final_k<<<1, 1, 0, stream>>>(accp, out);

    (void)in_sizes; (void)n_in; (void)out_size; (void)ws_size;
}

// Round 10
// 456.897 us; speedup vs baseline: 1.0513x; 1.0513x over previous
//
#include <hip/hip_runtime.h>

typedef unsigned short u16;
typedef unsigned int u32;
typedef __attribute__((ext_vector_type(8))) short bf8v;
typedef __attribute__((ext_vector_type(4))) float f4v;

#define RRELU_SLOPE 0.22916666667f

__device__ inline float bf2f(u16 u){ unsigned int i = ((unsigned int)u) << 16; float f; __builtin_memcpy(&f, &i, 4); return f; }
__device__ inline u16 f2bf(float f){ unsigned int i; __builtin_memcpy(&i, &f, 4); unsigned int r = (i + 0x7fffu + ((i >> 16) & 1u)) >> 16; return (u16)r; }
__device__ inline float frcp(float x){ return __builtin_amdgcn_rcpf(x); }
__device__ inline float fsigm(float x){ return frcp(1.f + __expf(-x)); }
__device__ inline float ftanh(float x){ return 2.f * frcp(1.f + __expf(-2.f * x)) - 1.f; }

// ---------------------------------------------------------------- prep: weight casts/transposes + ent cast + bias concat + edge histogram
__global__ __launch_bounds__(256) void prep_k(
    const float* __restrict__ Wn, const float* __restrict__ Wl, const float* __restrict__ We,
    const float* __restrict__ wih, const float* __restrict__ whh,
    const float* __restrict__ m1, const float* __restrict__ m2,
    const float* __restrict__ h1, const float* __restrict__ h2,
    const float* __restrict__ attn, const float* __restrict__ alg, const float* __restrict__ rel,
    const float* __restrict__ ent, const float* __restrict__ bat, const float* __restrict__ bh1,
    const int* __restrict__ edst, int E,
    u16* __restrict__ Bcat, u16* __restrict__ wihb, u16* __restrict__ whhb,
    u16* __restrict__ m1b, u16* __restrict__ m2b, u16* __restrict__ h1b, u16* __restrict__ h2b,
    u16* __restrict__ attnb, u16* __restrict__ algb, u16* __restrict__ relb,
    u16* __restrict__ entb, float* __restrict__ bias2, int* __restrict__ hist)
{
    int id = blockIdx.x * 256 + threadIdx.x;
    if (id < 49152) { // Bcat[n*384+k] : n in [0,128), k in [0,384)
        int n = id / 384, k = id % 384;
        float v = (k < 128) ? Wn[k*128 + n] : (k < 256 ? Wl[(k-128)*128 + n] : We[(k-256)*128 + n]);
        Bcat[id] = f2bf(v); return;
    }
    id -= 49152;
    if (id < 49152) { wihb[id] = f2bf(wih[id]); return; } id -= 49152;
    if (id < 49152) { whhb[id] = f2bf(whh[id]); return; } id -= 49152;
    if (id < 32768) { m1b[id]  = f2bf(m1[id]);  return; } id -= 32768;
    if (id < 32768) { m2b[id]  = f2bf(m2[id]);  return; } id -= 32768;
    if (id < 16384) { h1b[id]  = f2bf(h1[id]);  return; } id -= 16384;
    if (id < 16384) { h2b[id]  = f2bf(h2[id]);  return; } id -= 16384;
    if (id < 16384) { attnb[id]= f2bf(attn[id]);return; } id -= 16384;
    if (id < 16384) { algb[id] = f2bf(alg[id]); return; } id -= 16384;
    if (id < 58880) { relb[id] = f2bf(rel[id]); return; } id -= 58880;
    if (id < 2560000) { entb[id] = f2bf(ent[id]); return; } id -= 2560000;
    if (id < 256) { bias2[id] = (id < 128) ? bat[id] : bh1[id - 128]; return; } id -= 256;
    if (id < E) atomicAdd(&hist[edst[id]], 1);
}

// ---------------------------------------------------------------- exclusive scan over 20000 bins (1 block)
__global__ __launch_bounds__(1024) void scan_k(
    const int* __restrict__ hist, int* __restrict__ starts, int* __restrict__ cursor)
{
    __shared__ int part[1024];
    int t = threadIdx.x;
    int base = t * 20;
    int s = 0;
    for (int j = 0; j < 20; ++j) { int idx = base + j; if (idx < 20000) s += hist[idx]; }
    part[t] = s;
    __syncthreads();
    for (int off = 1; off < 1024; off <<= 1) {
        int v = (t >= off) ? part[t - off] : 0;
        __syncthreads();
        part[t] += v;
        __syncthreads();
    }
    int run = (t > 0) ? part[t - 1] : 0;
    for (int j = 0; j < 20; ++j) {
        int idx = base + j;
        if (idx < 20000) { starts[idx] = run; cursor[idx] = run; run += hist[idx]; }
    }
    if (t == 1023) starts[20000] = run;
}

// ---------------------------------------------------------------- co-dispatch: scatter edges (blocks < eb) | fused 2-layer rel map (8 blocks)
__global__ __launch_bounds__(256) void scmap_k(
    const int* __restrict__ src, const int* __restrict__ dst, const int* __restrict__ typ,
    int* __restrict__ cursor, int2* __restrict__ spack, int E, int eb,
    const u16* __restrict__ relb, const u16* __restrict__ m1b, const float* __restrict__ bm1,
    const u16* __restrict__ m2b, const float* __restrict__ bm2,
    u16* __restrict__ mapb, u16* __restrict__ mapT)
{
    __shared__ u16 t1l[4][16][264];
    int tid = threadIdx.x;
    if ((int)blockIdx.x < eb) {
        int e = blockIdx.x * 256 + tid;
        if (e >= E) return;
        int d = dst[e];
        int p = atomicAdd(&cursor[d], 1);
        spack[p] = make_int2(src[e], typ[e]);
        return;
    }
    // ---- fused rel map: rel -> t1(256) -> mapped_rel(128) (+ mapT)
    int wave = tid >> 6, lane = tid & 63;
    int ln = lane & 15, q = lane >> 4;
    int base = (blockIdx.x - eb) * 64 + wave * 16;
    int arow = base + ln; if (arow > 459) arow = 459;
    const u16* Ap = relb + arow * 128;
    f4v acc1[16] = {};
    for (int kc = 0; kc < 128; kc += 32) {
        bf8v af = *(const bf8v*)(Ap + kc + q*8);
#pragma unroll
        for (int nt = 0; nt < 16; ++nt) {
            bf8v bv = *(const bf8v*)(m1b + (nt*16 + ln)*128 + kc + q*8);
            acc1[nt] = __builtin_amdgcn_mfma_f32_16x16x32_bf16(af, bv, acc1[nt], 0, 0, 0);
        }
    }
#pragma unroll
    for (int nt = 0; nt < 16; ++nt) {
        int n = nt*16 + ln;
        float bv = bm1[n];
#pragma unroll
        for (int r = 0; r < 4; ++r)
            t1l[wave][q*4 + r][n] = f2bf(acc1[nt][r] + bv);
    }
    // wave-private staging: no block barrier needed
    f4v acc2[8] = {};
    for (int kc = 0; kc < 256; kc += 32) {
        bf8v af = *(const bf8v*)&t1l[wave][ln][kc + q*8];
#pragma unroll
        for (int nt = 0; nt < 8; ++nt) {
            bf8v bv = *(const bf8v*)(m2b + (nt*16 + ln)*256 + kc + q*8);
            acc2[nt] = __builtin_amdgcn_mfma_f32_16x16x32_bf16(af, bv, acc2[nt], 0, 0, 0);
        }
    }
#pragma unroll
    for (int nt = 0; nt < 8; ++nt) {
        int n = nt*16 + ln;
        float bv = bm2[n];
#pragma unroll
        for (int r = 0; r < 4; ++r) {
            int m = base + q*4 + r;
            if (m < 460) {
                u16 hv = f2bf(acc2[nt][r] + bv);
                mapb[m*128 + n] = hv;
                mapT[n*480 + m] = hv;
            }
        }
    }
}

// ---------------------------------------------------------------- co-dispatch: [agg gather, 5000 blocks x 4 INDEPENDENT waves,
//   one wave per entity, NO barrier, acat to global (round-7 dataflow)] | [q_rel gather -> attnq|th1 -> pred, 16 blocks]
__global__ __launch_bounds__(256) void aggq_k(
    const int2* __restrict__ spack, const int* __restrict__ starts,
    const u32* __restrict__ hb, const u32* __restrict__ rb, u32* __restrict__ Acat32,
    const u16* __restrict__ mapb, const int* __restrict__ trip,
    const u16* __restrict__ atb, const float* __restrict__ bias2,
    const u16* __restrict__ h2b, const float* __restrict__ bh2,
    u16* __restrict__ atq, float* __restrict__ pred, u16* __restrict__ X)
{
    __shared__ u16 th1l[4][16][136];   // qt branch only
    int tid = threadIdx.x;
    int wave = tid >> 6, lane = tid & 63;
    int ln = lane & 15, q = lane >> 4;
    if (blockIdx.x < 5000) {
        // one wave per entity, fully independent (no __syncthreads)
        int i = blockIdx.x * 4 + wave;
        int s0 = starts[i], s1 = starts[i + 1];
        float sx = 0.f, sy = 0.f;
        int e = s0;
        for (; e + 4 <= s1; e += 4) {
            int2 st0 = spack[e], st1 = spack[e+1], st2 = spack[e+2], st3 = spack[e+3];
            u32 a0 = hb[(long)st0.x * 64 + lane]; u32 r0 = rb[(long)st0.y * 64 + lane];
            u32 a1 = hb[(long)st1.x * 64 + lane]; u32 r1 = rb[(long)st1.y * 64 + lane];
            u32 a2 = hb[(long)st2.x * 64 + lane]; u32 r2 = rb[(long)st2.y * 64 + lane];
            u32 a3 = hb[(long)st3.x * 64 + lane]; u32 r3 = rb[(long)st3.y * 64 + lane];
            sx += bf2f((u16)(a0 & 0xffff)) + bf2f((u16)(r0 & 0xffff));
            sy += bf2f((u16)(a0 >> 16))    + bf2f((u16)(r0 >> 16));
            sx += bf2f((u16)(a1 & 0xffff)) + bf2f((u16)(r1 & 0xffff));
            sy += bf2f((u16)(a1 >> 16))    + bf2f((u16)(r1 >> 16));
            sx += bf2f((u16)(a2 & 0xffff)) + bf2f((u16)(r2 & 0xffff));
            sy += bf2f((u16)(a2 >> 16))    + bf2f((u16)(r2 >> 16));
            sx += bf2f((u16)(a3 & 0xffff)) + bf2f((u16)(r3 & 0xffff));
            sy += bf2f((u16)(a3 >> 16))    + bf2f((u16)(r3 >> 16));
        }
        for (; e < s1; ++e) {
            int2 st = spack[e];
            u32 a = hb[(long)st.x * 64 + lane];
            u32 r = rb[(long)st.y * 64 + lane];
            sx += bf2f((u16)(a & 0xffff)) + bf2f((u16)(r & 0xffff));
            sy += bf2f((u16)(a >> 16))    + bf2f((u16)(r >> 16));
        }
        bool has = s1 > s0;
        float nrm = has ? frcp((float)(s1 - s0)) : 0.f;
        u32 hv = hb[(long)i * 64 + lane];
        u32 agg = (u32)f2bf(sx * nrm) | ((u32)f2bf(sy * nrm) << 16);
        long o = (long)i * 192 + lane;
        Acat32[o]       = agg;
        Acat32[o + 64]  = has ? hv : 0u;
        Acat32[o + 128] = has ? 0u : hv;
        return;
    }
    // ---- fuse_qt branch: q_rel gather -> [attnq | th1] -> pred (+ X tail rows)
    int base = (blockIdx.x - 5000) * 64 + wave * 16;
    int ar = trip[(base + ln)*3 + 1];
    const u16* Ap = mapb + ar * 128;
    int rm_[4];
#pragma unroll
    for (int r = 0; r < 4; ++r) rm_[r] = trip[(base + q*4 + r)*3 + 1];
    f4v acc1[16] = {};
    for (int kc = 0; kc < 128; kc += 32) {
        bf8v af = *(const bf8v*)(Ap + kc + q*8);
#pragma unroll
        for (int nt = 0; nt < 16; ++nt) {
            bf8v bv = *(const bf8v*)(atb + (nt*16 + ln)*128 + kc + q*8);
            acc1[nt] = __builtin_amdgcn_mfma_f32_16x16x32_bf16(af, bv, acc1[nt], 0, 0, 0);
        }
    }
#pragma unroll
    for (int nt = 0; nt < 16; ++nt) {
        int n = nt*16 + ln;
        float bv = bias2[n];
#pragma unroll
        for (int r = 0; r < 4; ++r) {
            int m = base + q*4 + r;
            float x = acc1[nt][r] + bv;
            if (nt < 8) {
                atq[m*128 + n] = f2bf(x);
                X[(long)(8192 + m)*128 + n] = mapb[rm_[r]*128 + n];  // X tail = q_rel
            } else th1l[wave][q*4 + r][n - 128] = f2bf(x);
        }
    }
    // wave-private staging: no block barrier needed
    f4v acc2[8] = {};
    for (int kc = 0; kc < 128; kc += 32) {
        bf8v af = *(const bf8v*)&th1l[wave][ln][kc + q*8];
#pragma unroll
        for (int nt = 0; nt < 8; ++nt) {
            bf8v bv = *(const bf8v*)(h2b + (nt*16 + ln)*128 + kc + q*8);
            acc2[nt] = __builtin_amdgcn_mfma_f32_16x16x32_bf16(af, bv, acc2[nt], 0, 0, 0);
        }
    }
#pragma unroll
    for (int nt = 0; nt < 8; ++nt) {
        int n = nt*16 + ln;
        float bv = bh2[n];
#pragma unroll
        for (int r = 0; r < 4; ++r) {
            int m = base + q*4 + r;
            pred[(long)m*128 + n] = 0.1f * (acc2[nt][r] + bv) + bf2f(mapb[rm_[r]*128 + n]);
        }
    }
}

// ---------------------------------------------------------------- fused: pre_emb = rrelu(acat@Bcat^T) -> aligned = pre@W_align^T + b
// 313 blocks x 4 waves, 16 rows/wave, full 128 cols; pre staged wave-private  (round-7 proven)
__global__ __launch_bounds__(256) void prealn_k(
    const u16* __restrict__ acat, const u16* __restrict__ bcat,
    const u16* __restrict__ alb, const float* __restrict__ bal,
    u16* __restrict__ preb, u16* __restrict__ alnb)
{
    __shared__ u16 pl[4][16][136];
    int tid = threadIdx.x;
    int wave = tid >> 6, lane = tid & 63;
    int ln = lane & 15, q = lane >> 4;
    int bm = blockIdx.x * 64 + wave * 16;
    int am = bm + ln; if (am > 19999) am = 19999;
    const u16* Ap = acat + (long)am * 384;
    f4v acc[8] = {};
    for (int kc = 0; kc < 384; kc += 32) {
        bf8v af = *(const bf8v*)(Ap + kc + q*8);
#pragma unroll
        for (int nt = 0; nt < 8; ++nt) {
            bf8v bv = *(const bf8v*)(bcat + (nt*16 + ln)*384 + kc + q*8);
            acc[nt] = __builtin_amdgcn_mfma_f32_16x16x32_bf16(af, bv, acc[nt], 0, 0, 0);
        }
    }
#pragma unroll
    for (int nt = 0; nt < 8; ++nt) {
        int n = nt*16 + ln;
#pragma unroll
        for (int r = 0; r < 4; ++r) {
            int m = bm + q*4 + r;
            float v = acc[nt][r];
            v = (v >= 0.f) ? v : v * RRELU_SLOPE;
            u16 hv = f2bf(v);
            pl[wave][q*4 + r][n] = hv;
            if (m < 20000) preb[(long)m*128 + n] = hv;
        }
    }
    // wave-private staging: no block barrier needed
    f4v acc2[8] = {};
    for (int kc = 0; kc < 128; kc += 32) {
        bf8v af = *(const bf8v*)&pl[wave][ln][kc + q*8];
#pragma unroll
        for (int nt = 0; nt < 8; ++nt) {
            bf8v bv = *(const bf8v*)(alb + (nt*16 + ln)*128 + kc + q*8);
            acc2[nt] = __builtin_amdgcn_mfma_f32_16x16x32_bf16(af, bv, acc2[nt], 0, 0, 0);
        }
    }
#pragma unroll
    for (int nt = 0; nt < 8; ++nt) {
        int n = nt*16 + ln;
        float bv = bal[n];
#pragma unroll
        for (int r = 0; r < 4; ++r) {
            int m = bm + q*4 + r;
            if (m < 20000) alnb[(long)m*128 + n] = f2bf(acc2[nt][r] + bv);
        }
    }
}

// ---------------------------------------------------------------- fused A-rows + masked-softmax(460) + rel_path GEMM (K=480)
// block = 4 batch rows x 8 timesteps; A rows computed in-kernel via replicated-row MFMA
__global__ __launch_bounds__(256) void smrp_k(
    const u16* __restrict__ atq, const u16* __restrict__ mapb,
    const float* __restrict__ part, const u16* __restrict__ mapT, u16* __restrict__ X)
{
    __shared__ u16 xls[32][488];
    __shared__ float asl[4][464];
    int tid = threadIdx.x;
    int wave = tid >> 6, lane = tid & 63;
    int ln = lane & 15, q = lane >> 4;
    int b0 = blockIdx.x * 4;           // 256 blocks x 4 batch rows
    // A[db][n] = atq[b0+db] @ mapped_rel^T  (29 n-tiles strided over waves)
    {
        const u16* Ap = atq + (long)(b0 + (ln & 3)) * 128;
        bf8v af[4];
#pragma unroll
        for (int kc = 0; kc < 4; ++kc) af[kc] = *(const bf8v*)(Ap + kc*32 + q*8);
        for (int nt = wave; nt < 29; nt += 4) {
            int brow = nt*16 + ln; if (brow > 459) brow = 459;
            f4v acc = {};
#pragma unroll
            for (int kc = 0; kc < 4; ++kc) {
                bf8v bv = *(const bf8v*)(mapb + (long)brow*128 + kc*32 + q*8);
                acc = __builtin_amdgcn_mfma_f32_16x16x32_bf16(af[kc], bv, acc, 0, 0, 0);
            }
            if (q == 0) {
                int n = nt*16 + ln;
                if (n < 460) {
#pragma unroll
                    for (int r = 0; r < 4; ++r) asl[r][n] = acc[r];
                }
            }
        }
    }
    __syncthreads();
    for (int j = 0; j < 8; ++j) {
        int rl = wave*8 + j;           // rl = t*4 + db
        int t = rl >> 2, db = rl & 3;
        const float* crow = part + (long)(b0 + db)*3680 + t*460;
        float v[8], e[8];
        float m = -1e30f;
#pragma unroll
        for (int i = 0; i < 8; ++i) {
            int r = i*64 + lane;
            if (r < 460) {
                float x = crow[r] * asl[db][r];
                x = (x == 0.f) ? -1e9f : x;
                v[i] = x; m = fmaxf(m, x);
            } else v[i] = -1e30f;
        }
#pragma unroll
        for (int off = 32; off; off >>= 1) m = fmaxf(m, __shfl_xor(m, off));
        float sum = 0.f;
#pragma unroll
        for (int i = 0; i < 8; ++i) {
            int r = i*64 + lane;
            e[i] = 0.f;
            if (r < 460) { e[i] = __expf(v[i] - m); sum += e[i]; }
        }
#pragma unroll
        for (int off = 32; off; off >>= 1) sum += __shfl_xor(sum, off);
        float inv = frcp(sum);
#pragma unroll
        for (int i = 0; i < 8; ++i) {
            int r = i*64 + lane;
            if (r < 460)      xls[rl][r] = f2bf(e[i] * inv);
            else if (r < 488) xls[rl][r] = 0;
        }
    }
    __syncthreads();
    f4v acc[2][2] = {};
    for (int kc = 0; kc < 480; kc += 32) {
        bf8v a[2], bfr[2];
#pragma unroll
        for (int mt = 0; mt < 2; ++mt)
            a[mt] = *(const bf8v*)&xls[mt*16 + ln][kc + q*8];
#pragma unroll
        for (int nt = 0; nt < 2; ++nt)
            bfr[nt] = *(const bf8v*)(mapT + (wave*32 + nt*16 + ln)*480 + kc + q*8);
#pragma unroll
        for (int mt = 0; mt < 2; ++mt)
#pragma unroll
            for (int nt = 0; nt < 2; ++nt)
                acc[mt][nt] = __builtin_amdgcn_mfma_f32_16x16x32_bf16(a[mt], bfr[nt], acc[mt][nt], 0, 0, 0);
    }
#pragma unroll
    for (int mt = 0; mt < 2; ++mt)
#pragma unroll
    for (int nt = 0; nt < 2; ++nt) {
        int n = wave*32 + nt*16 + ln;
#pragma unroll
        for (int r = 0; r < 4; ++r) {
            int rl = mt*16 + q*4 + r;
            long m = (long)(rl >> 2)*1024 + b0 + (rl & 3);
            X[m*128 + n] = f2bf(acc[mt][nt][r]);
        }
    }
}

// ---------------------------------------------------------------- GRU scan: fused gi = X@wih^T, fused SubL prologue, fused V/obj epilogue
__global__ __launch_bounds__(256, 1) void gru_k(
    const u16* __restrict__ X, const u16* __restrict__ wihb, const float* __restrict__ bih,
    const u16* __restrict__ whhb, const float* __restrict__ bhh,
    const float* __restrict__ pred,
    const u16* __restrict__ preb, const u16* __restrict__ alb, const float* __restrict__ bal,
    const u16* __restrict__ AL, const int* __restrict__ trip,
    u16* __restrict__ V, float* __restrict__ accp)
{
    __shared__ u16  hbf[16][136];   // rows 4..15 stay zero
    __shared__ float hf [4][128];
    __shared__ float ghl[4][388];
    __shared__ float gil[4][388];
    __shared__ float sll[4][132];
    __shared__ float redm[4], redo[4];
    int tid = threadIdx.x;
    int wave = tid >> 6, lane = tid & 63;
    int ln = lane & 15, q = lane >> 4;
    int bb = blockIdx.x * 4;
    for (int i = tid; i < 16*136; i += 256) hbf[i/136][i%136] = 0;
    for (int i = tid; i < 4*128; i += 256) hf[i>>7][i&127] = 0.f;
    // preload whh + wih fragments: 6 N-tiles x 4 K-chunks per wave each (192 VGPRs; 1 blk/CU anyway)
    bf8v bfrag[6][4], wfrag[6][4];
#pragma unroll
    for (int nt = 0; nt < 6; ++nt)
#pragma unroll
        for (int kc = 0; kc < 4; ++kc) {
            bfrag[nt][kc] = *(const bf8v*)(whhb + (long)(wave*96 + nt*16 + ln)*128 + kc*32 + q*8);
            wfrag[nt][kc] = *(const bf8v*)(wihb + (long)(wave*96 + nt*16 + ln)*128 + kc*32 + q*8);
        }
    // SubL = pre_emb[trip[:,0]] @ W_align^T + b_align for this block's 4 rows
    {
        const u16* Pp = preb + (long)trip[(bb + (ln & 3))*3 + 0] * 128;
        f4v sacc[2] = {};
#pragma unroll
        for (int kc = 0; kc < 4; ++kc) {
            bf8v pf = *(const bf8v*)(Pp + kc*32 + q*8);
#pragma unroll
            for (int nt = 0; nt < 2; ++nt) {
                bf8v bv = *(const bf8v*)(alb + (long)(wave*32 + nt*16 + ln)*128 + kc*32 + q*8);
                sacc[nt] = __builtin_amdgcn_mfma_f32_16x16x32_bf16(pf, bv, sacc[nt], 0, 0, 0);
            }
        }
        if (q == 0) {
#pragma unroll
            for (int nt = 0; nt < 2; ++nt) {
                int n = wave*32 + nt*16 + ln;
                float bv = bal[n];
#pragma unroll
                for (int r = 0; r < 4; ++r) sll[r][n] = sacc[nt][r] + bv;
            }
        }
    }
    int k = tid & 127;
    float cr = bih[k] + bhh[k];
    float cz = bih[128 + k] + bhh[128 + k];
    float bin_ = bih[256 + k], bhn = bhh[256 + k];
    __syncthreads();
    float msum = 0.f, osum = 0.f;
    for (int t = 0; t <= 8; ++t) {
        float pv[2];
#pragma unroll
        for (int it = 0; it < 2; ++it) {
            int m = it*2 + (tid >> 7);
            pv[it] = (t >= 7) ? pred[(long)(bb + m)*128 + k] : 0.f;
        }
        if (t == 8) {
#pragma unroll
            for (int it = 0; it < 2; ++it) {
                int m = it*2 + (tid >> 7);
                hf[m][k] = pv[it]; hbf[m][k] = f2bf(pv[it]);
            }
            __syncthreads();
        }
        // gi = x_t @ wih^T (rows from X, 4-way replicated across lanes) ; gh = h @ whh^T
        long xr0 = (t < 8) ? ((long)t*1024 + bb) : (long)(8192 + bb);
        const u16* Xp = X + (xr0 + (ln & 3))*128;
        f4v gacc[6] = {};
        f4v acc[6] = {};
#pragma unroll
        for (int kc = 0; kc < 4; ++kc) {
            bf8v xf = *(const bf8v*)(Xp + kc*32 + q*8);
            bf8v af = *(const bf8v*)&hbf[ln][kc*32 + q*8];
#pragma unroll
            for (int nt = 0; nt < 6; ++nt) {
                gacc[nt] = __builtin_amdgcn_mfma_f32_16x16x32_bf16(xf, wfrag[nt][kc], gacc[nt], 0, 0, 0);
                acc[nt]  = __builtin_amdgcn_mfma_f32_16x16x32_bf16(af, bfrag[nt][kc], acc[nt],  0, 0, 0);
            }
        }
        if (q == 0) {
#pragma unroll
            for (int nt = 0; nt < 6; ++nt)
#pragma unroll
                for (int r = 0; r < 4; ++r) {
                    ghl[r][wave*96 + nt*16 + ln] = acc[nt][r];
                    gil[r][wave*96 + nt*16 + ln] = gacc[nt][r];
                }
        }
        __syncthreads();
#pragma unroll
        for (int it = 0; it < 2; ++it) {
            int m = it*2 + (tid >> 7);
            float rr = fsigm(gil[m][k] + ghl[m][k] + cr);
            float zz = fsigm(gil[m][128 + k] + ghl[m][128 + k] + cz);
            float nn = ftanh(gil[m][256 + k] + bin_ + rr * (ghl[m][256 + k] + bhn));
            float hn = (1.f - zz) * nn + zz * hf[m][k];
            if (t == 7) { float d = pv[it] - hn; msum += d*d; }
            if (t == 8) {
                u16 vb = f2bf(sll[m][k] * hn);
                V[(long)(bb + m)*128 + k] = vb;
                int obj = trip[(bb + m)*3 + 2];
                osum += bf2f(vb) * bf2f(AL[(long)obj*128 + k]);
            } else { hf[m][k] = hn; hbf[m][k] = f2bf(hn); }
        }
        __syncthreads();
    }
#pragma unroll
    for (int off = 32; off; off >>= 1) { msum += __shfl_down(msum, off); osum += __shfl_down(osum, off); }
    if (lane == 0) { redm[wave] = msum; redo[wave] = osum; }
    __syncthreads();
    if (tid == 0) {
        atomicAdd(accp + 0, redm[0] + redm[1] + redm[2] + redm[3]);
        atomicAdd(accp + 2, -(redo[0] + redo[1] + redo[2] + redo[3]));
    }
}

// ---------------------------------------------------------------- score GEMM: 8 waves x (64x32)/wave, half-tile LDS staging,
// full-line nt stores; grid (8,157): consecutive blocks share the AL column strip for L2 reuse.
// e = exp(-|s|), d = 1+e:  sigma = (s>=0 ? 1 : e)/d ;  softplus(s) = max(s,0) + log(d)
__global__ __launch_bounds__(512) void score_k(
    const u16* __restrict__ V, const u16* __restrict__ AL,
    float* __restrict__ out, float* __restrict__ sp_acc, int N)
{
    __shared__ float stage[8][1024];   // 32 rows x 32 cols f32 per wave (wave-private)
    int tid = threadIdx.x;
    int wave = tid >> 6, lane = tid & 63;
    int ln = lane & 15, q = lane >> 4;
    int bm = blockIdx.x * 128 + (wave >> 2) * 64;
    int bn = blockIdx.y * 128 + (wave & 3) * 32;
    bool valid = bn < N;               // N % 32 == 0 -> whole 32-col strip valid or not
    int br[2];
#pragma unroll
    for (int nt = 0; nt < 2; ++nt) { int n = bn + nt*16 + ln; br[nt] = (n < N) ? n : (N - 1); }
    f4v acc[4][2] = {};
    for (int kc = 0; kc < 128; kc += 32) {
        bf8v a[4], b[2];
#pragma unroll
        for (int mt = 0; mt < 4; ++mt)
            a[mt] = *(const bf8v*)(V + (long)(bm + mt*16 + ln)*128 + kc + q*8);
#pragma unroll
        for (int nt = 0; nt < 2; ++nt)
            b[nt] = *(const bf8v*)(AL + (long)br[nt]*128 + kc + q*8);
#pragma unroll
        for (int mt = 0; mt < 4; ++mt)
#pragma unroll
            for (int nt = 0; nt < 2; ++nt)
                acc[mt][nt] = __builtin_amdgcn_mfma_f32_16x16x32_bf16(a[mt], b[nt], acc[mt][nt], 0, 0, 0);
    }
    float lsum = 0.f;
    float* st = stage[wave];
#pragma unroll
    for (int half = 0; half < 2; ++half) {
#pragma unroll
        for (int mh = 0; mh < 2; ++mh) {
            int mt = half*2 + mh;
#pragma unroll
            for (int nt = 0; nt < 2; ++nt)
#pragma unroll
            for (int r = 0; r < 4; ++r) {
                float s = acc[mt][nt][r];
                float e = __expf(-fabsf(s));
                float d = 1.f + e;
                float inv = frcp(d);
                st[(mh*16 + q*4 + r)*32 + nt*16 + ln] = (s >= 0.f) ? inv : e * inv;
                lsum += fmaxf(s, 0.f) + __logf(d);
            }
        }
        // wave-private LDS: no block barrier needed; write full 128B lines
        if (valid) {
            int row0 = lane >> 3, c4 = (lane & 7) << 2;
#pragma unroll
            for (int i = 0; i < 4; ++i) {
                int row = i*8 + row0;
                f4v vv = *(const f4v*)&st[row*32 + c4];
                __builtin_nontemporal_store(vv, (f4v*)&out[(long)(bm + half*32 + row)*N + bn + c4]);
            }
        }
    }
    if (!valid) lsum = 0.f;
#pragma unroll
    for (int off = 32; off; off >>= 1) lsum += __shfl_xor(lsum, off);
    __shared__ float red[8];
    if (lane == 0) red[wave] = lsum;
    __syncthreads();
    if (tid == 0) {
        float tsum = 0.f;
#pragma unroll
        for (int w = 0; w < 8; ++w) tsum += red[w];
        atomicAdd(sp_acc, tsum);
    }
}

// ---------------------------------------------------------------- finalize scalars
__global__ void final_k(const float* __restrict__ acc, float* __restrict__ out)
{
    out[20480000] = acc[0] / (1024.f * 128.f);
    out[20480001] = (acc[1] + acc[2]) / (1024.f * 20000.f);
}

// ================================================================ host
extern "C" void kernel_launch(void* const* d_in, const int* in_sizes, int n_in,
                              void* d_out, int out_size, void* d_ws, size_t ws_size,
                              hipStream_t stream)
{
    const float* ent  = (const float*)d_in[0];
    const float* rel  = (const float*)d_in[1];
    const float* Wn   = (const float*)d_in[2];
    const float* Wl   = (const float*)d_in[3];
    const float* We   = (const float*)d_in[4];
    const float* wih  = (const float*)d_in[5];
    const float* whh  = (const float*)d_in[6];
    const float* b_ih = (const float*)d_in[7];
    const float* b_hh = (const float*)d_in[8];
    const float* Wm1  = (const float*)d_in[9];
    const float* bm1  = (const float*)d_in[10];
    const float* Wm2  = (const float*)d_in[11];
    const float* bm2  = (const float*)d_in[12];
    const float* Wh1  = (const float*)d_in[13];
    const float* bh1  = (const float*)d_in[14];
    const float* Wh2  = (const float*)d_in[15];
    const float* bh2  = (const float*)d_in[16];
    const float* Wal  = (const float*)d_in[17];
    const float* bal  = (const float*)d_in[18];
    const float* Wat  = (const float*)d_in[19];
    const float* bat  = (const float*)d_in[20];
    const float* part = (const float*)d_in[21];
    const int* esrc   = (const int*)d_in[22];
    const int* edst   = (const int*)d_in[23];
    const int* etyp   = (const int*)d_in[24];
    const int* trip   = (const int*)d_in[25];
    float* out = (float*)d_out;
    const int E = in_sizes[22];

    char* ws = (char*)d_ws;
    size_t off = 0;
    auto alloc = [&](size_t bytes) { size_t o = off; off = (off + bytes + 255) & ~(size_t)255; return o; };

    // zeroed region first (one memset)
    size_t o_acc   = alloc(256);                  // [0]=match [1]=softplus [2]=obj
    size_t o_hist  = alloc(20000 * 4);
    size_t o_mapT  = alloc(128 * 480 * 2);
    size_t zend = off;
    // non-zeroed
    size_t o_starts= alloc(20004 * 4);
    size_t o_cur   = alloc(20000 * 4);
    size_t o_spack = alloc((size_t)E * 8);
    size_t o_entb  = alloc((size_t)20000 * 128 * 2);
    size_t o_acat  = alloc((size_t)20000 * 384 * 2);
    size_t o_pre   = alloc((size_t)20000 * 128 * 2);
    size_t o_aln   = alloc((size_t)20000 * 128 * 2);
    size_t o_bcat  = alloc(128 * 384 * 2);
    size_t o_wih   = alloc(384 * 128 * 2);
    size_t o_whh   = alloc(384 * 128 * 2);
    size_t o_m1    = alloc(256 * 128 * 2);
    size_t o_m2    = alloc(128 * 256 * 2);
    size_t o_ath   = alloc(2 * 128 * 128 * 2);    // [W_attn ; W_h1] adjacent (N=256 stage-1)
    size_t o_h2    = alloc(128 * 128 * 2);
    size_t o_al    = alloc(128 * 128 * 2);
    size_t o_rel   = alloc(460 * 128 * 2);
    size_t o_map   = alloc(460 * 128 * 2);
    size_t o_atq   = alloc(1024 * 128 * 2);
    size_t o_b2    = alloc(256 * 4);              // [b_attn ; b_h1]
    size_t o_pred  = alloc(1024 * 128 * 4);
    size_t o_X     = alloc((size_t)9216 * 128 * 2);
    size_t o_V     = alloc(1024 * 128 * 2);

    float* accp  = (float*)(ws + o_acc);
    int* histp   = (int*)(ws + o_hist);
    u16* mapT    = (u16*)(ws + o_mapT);
    int* startsp = (int*)(ws + o_starts);
    int* curp    = (int*)(ws + o_cur);
    int2* spack  = (int2*)(ws + o_spack);
    u16* entb    = (u16*)(ws + o_entb);
    u16* acat    = (u16*)(ws + o_acat);
    u16* preb    = (u16*)(ws + o_pre);
    u16* alnb    = (u16*)(ws + o_aln);
    u16* bcat    = (u16*)(ws + o_bcat);
    u16* wihb    = (u16*)(ws + o_wih);
    u16* whhb    = (u16*)(ws + o_whh);
    u16* m1b     = (u16*)(ws + o_m1);
    u16* m2b     = (u16*)(ws + o_m2);
    u16* atb     = (u16*)(ws + o_ath);
    u16* h1b     = atb + 128 * 128;
    u16* h2b     = (u16*)(ws + o_h2);
    u16* alb     = (u16*)(ws + o_al);
    u16* relb    = (u16*)(ws + o_rel);
    u16* mapb    = (u16*)(ws + o_map);
    u16* atqb    = (u16*)(ws + o_atq);
    float* bias2 = (float*)(ws + o_b2);
    float* predf = (float*)(ws + o_pred);
    u16* Xb      = (u16*)(ws + o_X);
    u16* Vb      = (u16*)(ws + o_V);

    hipMemsetAsync(ws, 0, zend, stream);

    // prep covers: weights (337408) + ent cast (2560000) + bias concat (256) + edge histogram (E)
    int ptot = 2897664 + E;
    prep_k<<<(ptot + 255) / 256, 256, 0, stream>>>(
        Wn, Wl, We, wih, whh, Wm1, Wm2, Wh1, Wh2, Wat, Wal, rel,
        ent, bat, bh1, edst, E,
        bcat, wihb, whhb, m1b, m2b, h1b, h2b, atb, alb, relb,
        entb, bias2, histp);

    scan_k<<<1, 1024, 0, stream>>>(histp, startsp, curp);

    // co-dispatch: scatter (eb blocks) | rel-map (8 blocks)
    int eb = (E + 255) / 256;
    scmap_k<<<eb + 8, 256, 0, stream>>>(esrc, edst, etyp, curp, spack, E, eb,
                                        relb, m1b, bm1, m2b, bm2, mapb, mapT);

    // co-dispatch: agg gather (5000 blocks, 4 independent waves, acat->global) | q_rel->attnq/th1->pred (16 blocks)
    aggq_k<<<5016, 256, 0, stream>>>(spack, startsp, (const u32*)entb, (const u32*)relb, (u32*)acat,
                                     mapb, trip, atb, bias2, h2b, bh2, atqb, predf, Xb);

    // pre_emb + aligned_all fused  [20000 x 128] each
    prealn_k<<<313, 256, 0, stream>>>(acat, bcat, alb, bal, preb, alnb);

    // A-rows + softmax + rel_path fused -> X rows 0..8191 (bf16)
    smrp_k<<<256, 256, 0, stream>>>(atqb, mapb, part, mapT, Xb);

    // GRU scan with fused gi-GEMM, SubL prologue, V/obj epilogue
    gru_k<<<256, 256, 0, stream>>>(Xb, wihb, b_ih, whhb, b_hh, predf, preb, alb, bal, alnb, trip, Vb, accp);

    // score + softplus reduce  (grid: row-tiles fastest -> AL strip L2 reuse)
    score_k<<<dim3(8, 157), 512, 0, stream>>>(Vb, alnb, out, accp + 1, 20000);

    final_k<<<1, 1, 0, stream>>>(accp, out);

    (void)in_sizes; (void)n_in; (void)out_size; (void)ws_size;
}

// Round 11
// 419.655 us; speedup vs baseline: 1.1446x; 1.0887x over previous
//
#include <hip/hip_runtime.h>

typedef unsigned short u16;
typedef unsigned int u32;
typedef __attribute__((ext_vector_type(8))) short bf8v;
typedef __attribute__((ext_vector_type(4))) float f4v;

#define RRELU_SLOPE 0.22916666667f

__device__ inline float bf2f(u16 u){ unsigned int i = ((unsigned int)u) << 16; float f; __builtin_memcpy(&f, &i, 4); return f; }
__device__ inline u16 f2bf(float f){ unsigned int i; __builtin_memcpy(&i, &f, 4); unsigned int r = (i + 0x7fffu + ((i >> 16) & 1u)) >> 16; return (u16)r; }
__device__ inline float frcp(float x){ return __builtin_amdgcn_rcpf(x); }
__device__ inline float fsigm(float x){ return frcp(1.f + __expf(-x)); }
__device__ inline float ftanh(float x){ return 2.f * frcp(1.f + __expf(-2.f * x)) - 1.f; }

// ---------------------------------------------------------------- prep: weight casts/transposes + ent cast + bias concat + edge histogram
__global__ __launch_bounds__(256) void prep_k(
    const float* __restrict__ Wn, const float* __restrict__ Wl, const float* __restrict__ We,
    const float* __restrict__ wih, const float* __restrict__ whh,
    const float* __restrict__ m1, const float* __restrict__ m2,
    const float* __restrict__ h1, const float* __restrict__ h2,
    const float* __restrict__ attn, const float* __restrict__ alg, const float* __restrict__ rel,
    const float* __restrict__ ent, const float* __restrict__ bat, const float* __restrict__ bh1,
    const int* __restrict__ edst, int E,
    u16* __restrict__ Bcat, u16* __restrict__ wihb, u16* __restrict__ whhb,
    u16* __restrict__ m1b, u16* __restrict__ m2b, u16* __restrict__ h1b, u16* __restrict__ h2b,
    u16* __restrict__ attnb, u16* __restrict__ algb, u16* __restrict__ relb,
    u16* __restrict__ entb, float* __restrict__ bias2, int* __restrict__ hist)
{
    int id = blockIdx.x * 256 + threadIdx.x;
    if (id < 49152) { // Bcat[n*384+k] : n in [0,128), k in [0,384)
        int n = id / 384, k = id % 384;
        float v = (k < 128) ? Wn[k*128 + n] : (k < 256 ? Wl[(k-128)*128 + n] : We[(k-256)*128 + n]);
        Bcat[id] = f2bf(v); return;
    }
    id -= 49152;
    if (id < 49152) { wihb[id] = f2bf(wih[id]); return; } id -= 49152;
    if (id < 49152) { whhb[id] = f2bf(whh[id]); return; } id -= 49152;
    if (id < 32768) { m1b[id]  = f2bf(m1[id]);  return; } id -= 32768;
    if (id < 32768) { m2b[id]  = f2bf(m2[id]);  return; } id -= 32768;
    if (id < 16384) { h1b[id]  = f2bf(h1[id]);  return; } id -= 16384;
    if (id < 16384) { h2b[id]  = f2bf(h2[id]);  return; } id -= 16384;
    if (id < 16384) { attnb[id]= f2bf(attn[id]);return; } id -= 16384;
    if (id < 16384) { algb[id] = f2bf(alg[id]); return; } id -= 16384;
    if (id < 58880) { relb[id] = f2bf(rel[id]); return; } id -= 58880;
    if (id < 2560000) { entb[id] = f2bf(ent[id]); return; } id -= 2560000;
    if (id < 256) { bias2[id] = (id < 128) ? bat[id] : bh1[id - 128]; return; } id -= 256;
    if (id < E) atomicAdd(&hist[edst[id]], 1);
}

// ---------------------------------------------------------------- exclusive scan over 20000 bins (1 block)
__global__ __launch_bounds__(1024) void scan_k(
    const int* __restrict__ hist, int* __restrict__ starts, int* __restrict__ cursor)
{
    __shared__ int part[1024];
    int t = threadIdx.x;
    int base = t * 20;
    int s = 0;
    for (int j = 0; j < 20; ++j) { int idx = base + j; if (idx < 20000) s += hist[idx]; }
    part[t] = s;
    __syncthreads();
    for (int off = 1; off < 1024; off <<= 1) {
        int v = (t >= off) ? part[t - off] : 0;
        __syncthreads();
        part[t] += v;
        __syncthreads();
    }
    int run = (t > 0) ? part[t - 1] : 0;
    for (int j = 0; j < 20; ++j) {
        int idx = base + j;
        if (idx < 20000) { starts[idx] = run; cursor[idx] = run; run += hist[idx]; }
    }
    if (t == 1023) starts[20000] = run;
}

// ---------------------------------------------------------------- co-dispatch: scatter edges (blocks < eb) | fused 2-layer rel map (8 blocks)
__global__ __launch_bounds__(256) void scmap_k(
    const int* __restrict__ src, const int* __restrict__ dst, const int* __restrict__ typ,
    int* __restrict__ cursor, int2* __restrict__ spack, int E, int eb,
    const u16* __restrict__ relb, const u16* __restrict__ m1b, const float* __restrict__ bm1,
    const u16* __restrict__ m2b, const float* __restrict__ bm2,
    u16* __restrict__ mapb, u16* __restrict__ mapT)
{
    __shared__ u16 t1l[4][16][264];
    int tid = threadIdx.x;
    if ((int)blockIdx.x < eb) {
        int e = blockIdx.x * 256 + tid;
        if (e >= E) return;
        int d = dst[e];
        int p = atomicAdd(&cursor[d], 1);
        spack[p] = make_int2(src[e], typ[e]);
        return;
    }
    // ---- fused rel map: rel -> t1(256) -> mapped_rel(128) (+ mapT)
    int wave = tid >> 6, lane = tid & 63;
    int ln = lane & 15, q = lane >> 4;
    int base = (blockIdx.x - eb) * 64 + wave * 16;
    int arow = base + ln; if (arow > 459) arow = 459;
    const u16* Ap = relb + arow * 128;
    f4v acc1[16] = {};
    for (int kc = 0; kc < 128; kc += 32) {
        bf8v af = *(const bf8v*)(Ap + kc + q*8);
#pragma unroll
        for (int nt = 0; nt < 16; ++nt) {
            bf8v bv = *(const bf8v*)(m1b + (nt*16 + ln)*128 + kc + q*8);
            acc1[nt] = __builtin_amdgcn_mfma_f32_16x16x32_bf16(af, bv, acc1[nt], 0, 0, 0);
        }
    }
#pragma unroll
    for (int nt = 0; nt < 16; ++nt) {
        int n = nt*16 + ln;
        float bv = bm1[n];
#pragma unroll
        for (int r = 0; r < 4; ++r)
            t1l[wave][q*4 + r][n] = f2bf(acc1[nt][r] + bv);
    }
    // wave-private staging: no block barrier needed
    f4v acc2[8] = {};
    for (int kc = 0; kc < 256; kc += 32) {
        bf8v af = *(const bf8v*)&t1l[wave][ln][kc + q*8];
#pragma unroll
        for (int nt = 0; nt < 8; ++nt) {
            bf8v bv = *(const bf8v*)(m2b + (nt*16 + ln)*256 + kc + q*8);
            acc2[nt] = __builtin_amdgcn_mfma_f32_16x16x32_bf16(af, bv, acc2[nt], 0, 0, 0);
        }
    }
#pragma unroll
    for (int nt = 0; nt < 8; ++nt) {
        int n = nt*16 + ln;
        float bv = bm2[n];
#pragma unroll
        for (int r = 0; r < 4; ++r) {
            int m = base + q*4 + r;
            if (m < 460) {
                u16 hv = f2bf(acc2[nt][r] + bv);
                mapb[m*128 + n] = hv;
                mapT[n*480 + m] = hv;
            }
        }
    }
}

// ---------------------------------------------------------------- agg gather ONLY: 5000 blocks x 4 independent waves, one wave/entity,
// no LDS, no barrier, minimal VGPR -> max residency for latency hiding (round-7 dataflow, better occupancy shape)
__global__ __launch_bounds__(256) void agg_k(
    const int2* __restrict__ spack, const int* __restrict__ starts,
    const u32* __restrict__ hb, const u32* __restrict__ rb, u32* __restrict__ Acat32)
{
    int tid = threadIdx.x;
    int wave = tid >> 6, lane = tid & 63;
    int i = blockIdx.x * 4 + wave;
    int s0 = starts[i], s1 = starts[i + 1];
    float sx = 0.f, sy = 0.f;
    int e = s0;
    for (; e + 4 <= s1; e += 4) {
        int2 st0 = spack[e], st1 = spack[e+1], st2 = spack[e+2], st3 = spack[e+3];
        u32 a0 = hb[(long)st0.x * 64 + lane]; u32 r0 = rb[(long)st0.y * 64 + lane];
        u32 a1 = hb[(long)st1.x * 64 + lane]; u32 r1 = rb[(long)st1.y * 64 + lane];
        u32 a2 = hb[(long)st2.x * 64 + lane]; u32 r2 = rb[(long)st2.y * 64 + lane];
        u32 a3 = hb[(long)st3.x * 64 + lane]; u32 r3 = rb[(long)st3.y * 64 + lane];
        sx += bf2f((u16)(a0 & 0xffff)) + bf2f((u16)(r0 & 0xffff));
        sy += bf2f((u16)(a0 >> 16))    + bf2f((u16)(r0 >> 16));
        sx += bf2f((u16)(a1 & 0xffff)) + bf2f((u16)(r1 & 0xffff));
        sy += bf2f((u16)(a1 >> 16))    + bf2f((u16)(r1 >> 16));
        sx += bf2f((u16)(a2 & 0xffff)) + bf2f((u16)(r2 & 0xffff));
        sy += bf2f((u16)(a2 >> 16))    + bf2f((u16)(r2 >> 16));
        sx += bf2f((u16)(a3 & 0xffff)) + bf2f((u16)(r3 & 0xffff));
        sy += bf2f((u16)(a3 >> 16))    + bf2f((u16)(r3 >> 16));
    }
    for (; e < s1; ++e) {
        int2 st = spack[e];
        u32 a = hb[(long)st.x * 64 + lane];
        u32 r = rb[(long)st.y * 64 + lane];
        sx += bf2f((u16)(a & 0xffff)) + bf2f((u16)(r & 0xffff));
        sy += bf2f((u16)(a >> 16))    + bf2f((u16)(r >> 16));
    }
    bool has = s1 > s0;
    float nrm = has ? frcp((float)(s1 - s0)) : 0.f;
    u32 hv = hb[(long)i * 64 + lane];
    u32 agg = (u32)f2bf(sx * nrm) | ((u32)f2bf(sy * nrm) << 16);
    long o = (long)i * 192 + lane;
    Acat32[o]       = agg;
    Acat32[o + 64]  = has ? hv : 0u;
    Acat32[o + 128] = has ? 0u : hv;
}

// ---------------------------------------------------------------- co-dispatch: [pre_emb+aligned fused, 313 blocks] | [q_rel->attnq/th1->pred, 16 blocks]
__global__ __launch_bounds__(256) void prealnq_k(
    const u16* __restrict__ acat, const u16* __restrict__ bcat,
    const u16* __restrict__ alb, const float* __restrict__ bal,
    u16* __restrict__ preb, u16* __restrict__ alnb,
    const u16* __restrict__ mapb, const int* __restrict__ trip,
    const u16* __restrict__ atb, const float* __restrict__ bias2,
    const u16* __restrict__ h2b, const float* __restrict__ bh2,
    u16* __restrict__ atq, float* __restrict__ pred, u16* __restrict__ X)
{
    __shared__ u16 lds[4][16][136];    // pl (prealn) / th1l (qt) union
    int tid = threadIdx.x;
    int wave = tid >> 6, lane = tid & 63;
    int ln = lane & 15, q = lane >> 4;
    if (blockIdx.x < 313) {
        // ---- prealn branch: pre = rrelu(acat@Bcat^T) -> aligned = pre@W_align^T + b
        int bm = blockIdx.x * 64 + wave * 16;
        int am = bm + ln; if (am > 19999) am = 19999;
        const u16* Ap = acat + (long)am * 384;
        f4v acc[8] = {};
        for (int kc = 0; kc < 384; kc += 32) {
            bf8v af = *(const bf8v*)(Ap + kc + q*8);
#pragma unroll
            for (int nt = 0; nt < 8; ++nt) {
                bf8v bv = *(const bf8v*)(bcat + (nt*16 + ln)*384 + kc + q*8);
                acc[nt] = __builtin_amdgcn_mfma_f32_16x16x32_bf16(af, bv, acc[nt], 0, 0, 0);
            }
        }
#pragma unroll
        for (int nt = 0; nt < 8; ++nt) {
            int n = nt*16 + ln;
#pragma unroll
            for (int r = 0; r < 4; ++r) {
                int m = bm + q*4 + r;
                float v = acc[nt][r];
                v = (v >= 0.f) ? v : v * RRELU_SLOPE;
                u16 hv = f2bf(v);
                lds[wave][q*4 + r][n] = hv;
                if (m < 20000) preb[(long)m*128 + n] = hv;
            }
        }
        // wave-private staging: no block barrier needed
        f4v acc2[8] = {};
        for (int kc = 0; kc < 128; kc += 32) {
            bf8v af = *(const bf8v*)&lds[wave][ln][kc + q*8];
#pragma unroll
            for (int nt = 0; nt < 8; ++nt) {
                bf8v bv = *(const bf8v*)(alb + (nt*16 + ln)*128 + kc + q*8);
                acc2[nt] = __builtin_amdgcn_mfma_f32_16x16x32_bf16(af, bv, acc2[nt], 0, 0, 0);
            }
        }
#pragma unroll
        for (int nt = 0; nt < 8; ++nt) {
            int n = nt*16 + ln;
            float bv = bal[n];
#pragma unroll
            for (int r = 0; r < 4; ++r) {
                int m = bm + q*4 + r;
                if (m < 20000) alnb[(long)m*128 + n] = f2bf(acc2[nt][r] + bv);
            }
        }
        return;
    }
    // ---- qt branch: q_rel gather -> [attnq | th1] -> pred (+ X tail rows)
    int base = (blockIdx.x - 313) * 64 + wave * 16;
    int ar = trip[(base + ln)*3 + 1];
    const u16* Ap = mapb + ar * 128;
    int rm_[4];
#pragma unroll
    for (int r = 0; r < 4; ++r) rm_[r] = trip[(base + q*4 + r)*3 + 1];
    f4v acc1[16] = {};
    for (int kc = 0; kc < 128; kc += 32) {
        bf8v af = *(const bf8v*)(Ap + kc + q*8);
#pragma unroll
        for (int nt = 0; nt < 16; ++nt) {
            bf8v bv = *(const bf8v*)(atb + (nt*16 + ln)*128 + kc + q*8);
            acc1[nt] = __builtin_amdgcn_mfma_f32_16x16x32_bf16(af, bv, acc1[nt], 0, 0, 0);
        }
    }
#pragma unroll
    for (int nt = 0; nt < 16; ++nt) {
        int n = nt*16 + ln;
        float bv = bias2[n];
#pragma unroll
        for (int r = 0; r < 4; ++r) {
            int m = base + q*4 + r;
            float x = acc1[nt][r] + bv;
            if (nt < 8) {
                atq[m*128 + n] = f2bf(x);
                X[(long)(8192 + m)*128 + n] = mapb[rm_[r]*128 + n];  // X tail = q_rel
            } else lds[wave][q*4 + r][n - 128] = f2bf(x);
        }
    }
    // wave-private staging: no block barrier needed
    f4v acc2[8] = {};
    for (int kc = 0; kc < 128; kc += 32) {
        bf8v af = *(const bf8v*)&lds[wave][ln][kc + q*8];
#pragma unroll
        for (int nt = 0; nt < 8; ++nt) {
            bf8v bv = *(const bf8v*)(h2b + (nt*16 + ln)*128 + kc + q*8);
            acc2[nt] = __builtin_amdgcn_mfma_f32_16x16x32_bf16(af, bv, acc2[nt], 0, 0, 0);
        }
    }
#pragma unroll
    for (int nt = 0; nt < 8; ++nt) {
        int n = nt*16 + ln;
        float bv = bh2[n];
#pragma unroll
        for (int r = 0; r < 4; ++r) {
            int m = base + q*4 + r;
            pred[(long)m*128 + n] = 0.1f * (acc2[nt][r] + bv) + bf2f(mapb[rm_[r]*128 + n]);
        }
    }
}

// ---------------------------------------------------------------- fused A-rows + masked-softmax(460) + rel_path GEMM (K=480)
// block = 4 batch rows x 8 timesteps; A rows computed in-kernel via replicated-row MFMA
__global__ __launch_bounds__(256) void smrp_k(
    const u16* __restrict__ atq, const u16* __restrict__ mapb,
    const float* __restrict__ part, const u16* __restrict__ mapT, u16* __restrict__ X)
{
    __shared__ u16 xls[32][488];
    __shared__ float asl[4][464];
    int tid = threadIdx.x;
    int wave = tid >> 6, lane = tid & 63;
    int ln = lane & 15, q = lane >> 4;
    int b0 = blockIdx.x * 4;           // 256 blocks x 4 batch rows
    // A[db][n] = atq[b0+db] @ mapped_rel^T  (29 n-tiles strided over waves)
    {
        const u16* Ap = atq + (long)(b0 + (ln & 3)) * 128;
        bf8v af[4];
#pragma unroll
        for (int kc = 0; kc < 4; ++kc) af[kc] = *(const bf8v*)(Ap + kc*32 + q*8);
        for (int nt = wave; nt < 29; nt += 4) {
            int brow = nt*16 + ln; if (brow > 459) brow = 459;
            f4v acc = {};
#pragma unroll
            for (int kc = 0; kc < 4; ++kc) {
                bf8v bv = *(const bf8v*)(mapb + (long)brow*128 + kc*32 + q*8);
                acc = __builtin_amdgcn_mfma_f32_16x16x32_bf16(af[kc], bv, acc, 0, 0, 0);
            }
            if (q == 0) {
                int n = nt*16 + ln;
                if (n < 460) {
#pragma unroll
                    for (int r = 0; r < 4; ++r) asl[r][n] = acc[r];
                }
            }
        }
    }
    __syncthreads();
    for (int j = 0; j < 8; ++j) {
        int rl = wave*8 + j;           // rl = t*4 + db
        int t = rl >> 2, db = rl & 3;
        const float* crow = part + (long)(b0 + db)*3680 + t*460;
        float v[8], e[8];
        float m = -1e30f;
#pragma unroll
        for (int i = 0; i < 8; ++i) {
            int r = i*64 + lane;
            if (r < 460) {
                float x = crow[r] * asl[db][r];
                x = (x == 0.f) ? -1e9f : x;
                v[i] = x; m = fmaxf(m, x);
            } else v[i] = -1e30f;
        }
#pragma unroll
        for (int off = 32; off; off >>= 1) m = fmaxf(m, __shfl_xor(m, off));
        float sum = 0.f;
#pragma unroll
        for (int i = 0; i < 8; ++i) {
            int r = i*64 + lane;
            e[i] = 0.f;
            if (r < 460) { e[i] = __expf(v[i] - m); sum += e[i]; }
        }
#pragma unroll
        for (int off = 32; off; off >>= 1) sum += __shfl_xor(sum, off);
        float inv = frcp(sum);
#pragma unroll
        for (int i = 0; i < 8; ++i) {
            int r = i*64 + lane;
            if (r < 460)      xls[rl][r] = f2bf(e[i] * inv);
            else if (r < 488) xls[rl][r] = 0;
        }
    }
    __syncthreads();
    f4v acc[2][2] = {};
    for (int kc = 0; kc < 480; kc += 32) {
        bf8v a[2], bfr[2];
#pragma unroll
        for (int mt = 0; mt < 2; ++mt)
            a[mt] = *(const bf8v*)&xls[mt*16 + ln][kc + q*8];
#pragma unroll
        for (int nt = 0; nt < 2; ++nt)
            bfr[nt] = *(const bf8v*)(mapT + (wave*32 + nt*16 + ln)*480 + kc + q*8);
#pragma unroll
        for (int mt = 0; mt < 2; ++mt)
#pragma unroll
            for (int nt = 0; nt < 2; ++nt)
                acc[mt][nt] = __builtin_amdgcn_mfma_f32_16x16x32_bf16(a[mt], bfr[nt], acc[mt][nt], 0, 0, 0);
    }
#pragma unroll
    for (int mt = 0; mt < 2; ++mt)
#pragma unroll
    for (int nt = 0; nt < 2; ++nt) {
        int n = wave*32 + nt*16 + ln;
#pragma unroll
        for (int r = 0; r < 4; ++r) {
            int rl = mt*16 + q*4 + r;
            long m = (long)(rl >> 2)*1024 + b0 + (rl & 3);
            X[m*128 + n] = f2bf(acc[mt][nt][r]);
        }
    }
}

// ---------------------------------------------------------------- GRU scan: fused gi = X@wih^T, fused SubL prologue, fused V/obj epilogue
__global__ __launch_bounds__(256, 1) void gru_k(
    const u16* __restrict__ X, const u16* __restrict__ wihb, const float* __restrict__ bih,
    const u16* __restrict__ whhb, const float* __restrict__ bhh,
    const float* __restrict__ pred,
    const u16* __restrict__ preb, const u16* __restrict__ alb, const float* __restrict__ bal,
    const u16* __restrict__ AL, const int* __restrict__ trip,
    u16* __restrict__ V, float* __restrict__ accp)
{
    __shared__ u16  hbf[16][136];   // rows 4..15 stay zero
    __shared__ float hf [4][128];
    __shared__ float ghl[4][388];
    __shared__ float gil[4][388];
    __shared__ float sll[4][132];
    __shared__ float redm[4], redo[4];
    int tid = threadIdx.x;
    int wave = tid >> 6, lane = tid & 63;
    int ln = lane & 15, q = lane >> 4;
    int bb = blockIdx.x * 4;
    for (int i = tid; i < 16*136; i += 256) hbf[i/136][i%136] = 0;
    for (int i = tid; i < 4*128; i += 256) hf[i>>7][i&127] = 0.f;
    // preload whh + wih fragments: 6 N-tiles x 4 K-chunks per wave each (192 VGPRs; 1 blk/CU anyway)
    bf8v bfrag[6][4], wfrag[6][4];
#pragma unroll
    for (int nt = 0; nt < 6; ++nt)
#pragma unroll
        for (int kc = 0; kc < 4; ++kc) {
            bfrag[nt][kc] = *(const bf8v*)(whhb + (long)(wave*96 + nt*16 + ln)*128 + kc*32 + q*8);
            wfrag[nt][kc] = *(const bf8v*)(wihb + (long)(wave*96 + nt*16 + ln)*128 + kc*32 + q*8);
        }
    // SubL = pre_emb[trip[:,0]] @ W_align^T + b_align for this block's 4 rows
    {
        const u16* Pp = preb + (long)trip[(bb + (ln & 3))*3 + 0] * 128;
        f4v sacc[2] = {};
#pragma unroll
        for (int kc = 0; kc < 4; ++kc) {
            bf8v pf = *(const bf8v*)(Pp + kc*32 + q*8);
#pragma unroll
            for (int nt = 0; nt < 2; ++nt) {
                bf8v bv = *(const bf8v*)(alb + (long)(wave*32 + nt*16 + ln)*128 + kc*32 + q*8);
                sacc[nt] = __builtin_amdgcn_mfma_f32_16x16x32_bf16(pf, bv, sacc[nt], 0, 0, 0);
            }
        }
        if (q == 0) {
#pragma unroll
            for (int nt = 0; nt < 2; ++nt) {
                int n = wave*32 + nt*16 + ln;
                float bv = bal[n];
#pragma unroll
                for (int r = 0; r < 4; ++r) sll[r][n] = sacc[nt][r] + bv;
            }
        }
    }
    int k = tid & 127;
    float cr = bih[k] + bhh[k];
    float cz = bih[128 + k] + bhh[128 + k];
    float bin_ = bih[256 + k], bhn = bhh[256 + k];
    __syncthreads();
    float msum = 0.f, osum = 0.f;
    for (int t = 0; t <= 8; ++t) {
        float pv[2];
#pragma unroll
        for (int it = 0; it < 2; ++it) {
            int m = it*2 + (tid >> 7);
            pv[it] = (t >= 7) ? pred[(long)(bb + m)*128 + k] : 0.f;
        }
        if (t == 8) {
#pragma unroll
            for (int it = 0; it < 2; ++it) {
                int m = it*2 + (tid >> 7);
                hf[m][k] = pv[it]; hbf[m][k] = f2bf(pv[it]);
            }
            __syncthreads();
        }
        // gi = x_t @ wih^T (rows from X, 4-way replicated across lanes) ; gh = h @ whh^T
        long xr0 = (t < 8) ? ((long)t*1024 + bb) : (long)(8192 + bb);
        const u16* Xp = X + (xr0 + (ln & 3))*128;
        f4v gacc[6] = {};
        f4v acc[6] = {};
#pragma unroll
        for (int kc = 0; kc < 4; ++kc) {
            bf8v xf = *(const bf8v*)(Xp + kc*32 + q*8);
            bf8v af = *(const bf8v*)&hbf[ln][kc*32 + q*8];
#pragma unroll
            for (int nt = 0; nt < 6; ++nt) {
                gacc[nt] = __builtin_amdgcn_mfma_f32_16x16x32_bf16(xf, wfrag[nt][kc], gacc[nt], 0, 0, 0);
                acc[nt]  = __builtin_amdgcn_mfma_f32_16x16x32_bf16(af, bfrag[nt][kc], acc[nt],  0, 0, 0);
            }
        }
        if (q == 0) {
#pragma unroll
            for (int nt = 0; nt < 6; ++nt)
#pragma unroll
                for (int r = 0; r < 4; ++r) {
                    ghl[r][wave*96 + nt*16 + ln] = acc[nt][r];
                    gil[r][wave*96 + nt*16 + ln] = gacc[nt][r];
                }
        }
        __syncthreads();
#pragma unroll
        for (int it = 0; it < 2; ++it) {
            int m = it*2 + (tid >> 7);
            float rr = fsigm(gil[m][k] + ghl[m][k] + cr);
            float zz = fsigm(gil[m][128 + k] + ghl[m][128 + k] + cz);
            float nn = ftanh(gil[m][256 + k] + bin_ + rr * (ghl[m][256 + k] + bhn));
            float hn = (1.f - zz) * nn + zz * hf[m][k];
            if (t == 7) { float d = pv[it] - hn; msum += d*d; }
            if (t == 8) {
                u16 vb = f2bf(sll[m][k] * hn);
                V[(long)(bb + m)*128 + k] = vb;
                int obj = trip[(bb + m)*3 + 2];
                osum += bf2f(vb) * bf2f(AL[(long)obj*128 + k]);
            } else { hf[m][k] = hn; hbf[m][k] = f2bf(hn); }
        }
        __syncthreads();
    }
#pragma unroll
    for (int off = 32; off; off >>= 1) { msum += __shfl_down(msum, off); osum += __shfl_down(osum, off); }
    if (lane == 0) { redm[wave] = msum; redo[wave] = osum; }
    __syncthreads();
    if (tid == 0) {
        atomicAdd(accp + 0, redm[0] + redm[1] + redm[2] + redm[3]);
        atomicAdd(accp + 2, -(redo[0] + redo[1] + redo[2] + redo[3]));
    }
}

// ---------------------------------------------------------------- score GEMM: 8 waves x (64x32)/wave, half-tile LDS staging,
// full-line nt stores; grid (8,157): consecutive blocks share the AL column strip for L2 reuse.
// e = exp(-|s|), d = 1+e:  sigma = (s>=0 ? 1 : e)/d ;  softplus(s) = max(s,0) + log(d)
__global__ __launch_bounds__(512) void score_k(
    const u16* __restrict__ V, const u16* __restrict__ AL,
    float* __restrict__ out, float* __restrict__ sp_acc, int N)
{
    __shared__ float stage[8][1024];   // 32 rows x 32 cols f32 per wave (wave-private)
    int tid = threadIdx.x;
    int wave = tid >> 6, lane = tid & 63;
    int ln = lane & 15, q = lane >> 4;
    int bm = blockIdx.x * 128 + (wave >> 2) * 64;
    int bn = blockIdx.y * 128 + (wave & 3) * 32;
    bool valid = bn < N;               // N % 32 == 0 -> whole 32-col strip valid or not
    int br[2];
#pragma unroll
    for (int nt = 0; nt < 2; ++nt) { int n = bn + nt*16 + ln; br[nt] = (n < N) ? n : (N - 1); }
    f4v acc[4][2] = {};
    for (int kc = 0; kc < 128; kc += 32) {
        bf8v a[4], b[2];
#pragma unroll
        for (int mt = 0; mt < 4; ++mt)
            a[mt] = *(const bf8v*)(V + (long)(bm + mt*16 + ln)*128 + kc + q*8);
#pragma unroll
        for (int nt = 0; nt < 2; ++nt)
            b[nt] = *(const bf8v*)(AL + (long)br[nt]*128 + kc + q*8);
#pragma unroll
        for (int mt = 0; mt < 4; ++mt)
#pragma unroll
            for (int nt = 0; nt < 2; ++nt)
                acc[mt][nt] = __builtin_amdgcn_mfma_f32_16x16x32_bf16(a[mt], b[nt], acc[mt][nt], 0, 0, 0);
    }
    float lsum = 0.f;
    float* st = stage[wave];
#pragma unroll
    for (int half = 0; half < 2; ++half) {
#pragma unroll
        for (int mh = 0; mh < 2; ++mh) {
            int mt = half*2 + mh;
#pragma unroll
            for (int nt = 0; nt < 2; ++nt)
#pragma unroll
            for (int r = 0; r < 4; ++r) {
                float s = acc[mt][nt][r];
                float e = __expf(-fabsf(s));
                float d = 1.f + e;
                float inv = frcp(d);
                st[(mh*16 + q*4 + r)*32 + nt*16 + ln] = (s >= 0.f) ? inv : e * inv;
                lsum += fmaxf(s, 0.f) + __logf(d);
            }
        }
        // wave-private LDS: no block barrier needed; write full 128B lines
        if (valid) {
            int row0 = lane >> 3, c4 = (lane & 7) << 2;
#pragma unroll
            for (int i = 0; i < 4; ++i) {
                int row = i*8 + row0;
                f4v vv = *(const f4v*)&st[row*32 + c4];
                __builtin_nontemporal_store(vv, (f4v*)&out[(long)(bm + half*32 + row)*N + bn + c4]);
            }
        }
    }
    if (!valid) lsum = 0.f;
#pragma unroll
    for (int off = 32; off; off >>= 1) lsum += __shfl_xor(lsum, off);
    __shared__ float red[8];
    if (lane == 0) red[wave] = lsum;
    __syncthreads();
    if (tid == 0) {
        float tsum = 0.f;
#pragma unroll
        for (int w = 0; w < 8; ++w) tsum += red[w];
        atomicAdd(sp_acc, tsum);
    }
}

// ---------------------------------------------------------------- finalize scalars
__global__ void final_k(const float* __restrict__ acc, float* __restrict__ out)
{
    out[20480000] = acc[0] / (1024.f * 128.f);
    out[20480001] = (acc[1] + acc[2]) / (1024.f * 20000.f);
}

// ================================================================ host
extern "C" void kernel_launch(void* const* d_in, const int* in_sizes, int n_in,
                              void* d_out, int out_size, void* d_ws, size_t ws_size,
                              hipStream_t stream)
{
    const float* ent  = (const float*)d_in[0];
    const float* rel  = (const float*)d_in[1];
    const float* Wn   = (const float*)d_in[2];
    const float* Wl   = (const float*)d_in[3];
    const float* We   = (const float*)d_in[4];
    const float* wih  = (const float*)d_in[5];
    const float* whh  = (const float*)d_in[6];
    const float* b_ih = (const float*)d_in[7];
    const float* b_hh = (const float*)d_in[8];
    const float* Wm1  = (const float*)d_in[9];
    const float* bm1  = (const float*)d_in[10];
    const float* Wm2  = (const float*)d_in[11];
    const float* bm2  = (const float*)d_in[12];
    const float* Wh1  = (const float*)d_in[13];
    const float* bh1  = (const float*)d_in[14];
    const float* Wh2  = (const float*)d_in[15];
    const float* bh2  = (const float*)d_in[16];
    const float* Wal  = (const float*)d_in[17];
    const float* bal  = (const float*)d_in[18];
    const float* Wat  = (const float*)d_in[19];
    const float* bat  = (const float*)d_in[20];
    const float* part = (const float*)d_in[21];
    const int* esrc   = (const int*)d_in[22];
    const int* edst   = (const int*)d_in[23];
    const int* etyp   = (const int*)d_in[24];
    const int* trip   = (const int*)d_in[25];
    float* out = (float*)d_out;
    const int E = in_sizes[22];

    char* ws = (char*)d_ws;
    size_t off = 0;
    auto alloc = [&](size_t bytes) { size_t o = off; off = (off + bytes + 255) & ~(size_t)255; return o; };

    // zeroed region first (one memset)
    size_t o_acc   = alloc(256);                  // [0]=match [1]=softplus [2]=obj
    size_t o_hist  = alloc(20000 * 4);
    size_t o_mapT  = alloc(128 * 480 * 2);
    size_t zend = off;
    // non-zeroed
    size_t o_starts= alloc(20004 * 4);
    size_t o_cur   = alloc(20000 * 4);
    size_t o_spack = alloc((size_t)E * 8);
    size_t o_entb  = alloc((size_t)20000 * 128 * 2);
    size_t o_acat  = alloc((size_t)20000 * 384 * 2);
    size_t o_pre   = alloc((size_t)20000 * 128 * 2);
    size_t o_aln   = alloc((size_t)20000 * 128 * 2);
    size_t o_bcat  = alloc(128 * 384 * 2);
    size_t o_wih   = alloc(384 * 128 * 2);
    size_t o_whh   = alloc(384 * 128 * 2);
    size_t o_m1    = alloc(256 * 128 * 2);
    size_t o_m2    = alloc(128 * 256 * 2);
    size_t o_ath   = alloc(2 * 128 * 128 * 2);    // [W_attn ; W_h1] adjacent (N=256 stage-1)
    size_t o_h2    = alloc(128 * 128 * 2);
    size_t o_al    = alloc(128 * 128 * 2);
    size_t o_rel   = alloc(460 * 128 * 2);
    size_t o_map   = alloc(460 * 128 * 2);
    size_t o_atq   = alloc(1024 * 128 * 2);
    size_t o_b2    = alloc(256 * 4);              // [b_attn ; b_h1]
    size_t o_pred  = alloc(1024 * 128 * 4);
    size_t o_X     = alloc((size_t)9216 * 128 * 2);
    size_t o_V     = alloc(1024 * 128 * 2);

    float* accp  = (float*)(ws + o_acc);
    int* histp   = (int*)(ws + o_hist);
    u16* mapT    = (u16*)(ws + o_mapT);
    int* startsp = (int*)(ws + o_starts);
    int* curp    = (int*)(ws + o_cur);
    int2* spack  = (int2*)(ws + o_spack);
    u16* entb    = (u16*)(ws + o_entb);
    u16* acat    = (u16*)(ws + o_acat);
    u16* preb    = (u16*)(ws + o_pre);
    u16* alnb    = (u16*)(ws + o_aln);
    u16* bcat    = (u16*)(ws + o_bcat);
    u16* wihb    = (u16*)(ws + o_wih);
    u16* whhb    = (u16*)(ws + o_whh);
    u16* m1b     = (u16*)(ws + o_m1);
    u16* m2b     = (u16*)(ws + o_m2);
    u16* atb     = (u16*)(ws + o_ath);
    u16* h1b     = atb + 128 * 128;
    u16* h2b     = (u16*)(ws + o_h2);
    u16* alb     = (u16*)(ws + o_al);
    u16* relb    = (u16*)(ws + o_rel);
    u16* mapb    = (u16*)(ws + o_map);
    u16* atqb    = (u16*)(ws + o_atq);
    float* bias2 = (float*)(ws + o_b2);
    float* predf = (float*)(ws + o_pred);
    u16* Xb      = (u16*)(ws + o_X);
    u16* Vb      = (u16*)(ws + o_V);

    hipMemsetAsync(ws, 0, zend, stream);

    // prep covers: weights (337408) + ent cast (2560000) + bias concat (256) + edge histogram (E)
    int ptot = 2897664 + E;
    prep_k<<<(ptot + 255) / 256, 256, 0, stream>>>(
        Wn, Wl, We, wih, whh, Wm1, Wm2, Wh1, Wh2, Wat, Wal, rel,
        ent, bat, bh1, edst, E,
        bcat, wihb, whhb, m1b, m2b, h1b, h2b, atb, alb, relb,
        entb, bias2, histp);

    scan_k<<<1, 1024, 0, stream>>>(histp, startsp, curp);

    // co-dispatch: scatter (eb blocks) | rel-map (8 blocks)
    int eb = (E + 255) / 256;
    scmap_k<<<eb + 8, 256, 0, stream>>>(esrc, edst, etyp, curp, spack, E, eb,
                                        relb, m1b, bm1, m2b, bm2, mapb, mapT);

    // agg gather only: 5000 blocks x 4 independent waves, minimal footprint
    agg_k<<<5000, 256, 0, stream>>>(spack, startsp, (const u32*)entb, (const u32*)relb, (u32*)acat);

    // co-dispatch: pre_emb+aligned fused (313 blocks) | q_rel->attnq/th1->pred (16 blocks)
    prealnq_k<<<329, 256, 0, stream>>>(acat, bcat, alb, bal, preb, alnb,
                                       mapb, trip, atb, bias2, h2b, bh2, atqb, predf, Xb);

    // A-rows + softmax + rel_path fused -> X rows 0..8191 (bf16)
    smrp_k<<<256, 256, 0, stream>>>(atqb, mapb, part, mapT, Xb);

    // GRU scan with fused gi-GEMM, SubL prologue, V/obj epilogue
    gru_k<<<256, 256, 0, stream>>>(Xb, wihb, b_ih, whhb, b_hh, predf, preb, alb, bal, alnb, trip, Vb, accp);

    // score + softplus reduce  (grid: row-tiles fastest -> AL strip L2 reuse)
    score_k<<<dim3(8, 157), 512, 0, stream>>>(Vb, alnb, out, accp + 1, 20000);

    final_k<<<1, 1, 0, stream>>>(accp, out);

    (void)in_sizes; (void)n_in; (void)out_size; (void)ws_size;
}

// Round 12
// 398.239 us; speedup vs baseline: 1.2062x; 1.0538x over previous
//
#include <hip/hip_runtime.h>

typedef unsigned short u16;
typedef unsigned int u32;
typedef __attribute__((ext_vector_type(8))) short bf8v;
typedef __attribute__((ext_vector_type(4))) float f4v;

#define RRELU_SLOPE 0.22916666667f

__device__ inline float bf2f(u16 u){ unsigned int i = ((unsigned int)u) << 16; float f; __builtin_memcpy(&f, &i, 4); return f; }
__device__ inline u16 f2bf(float f){ unsigned int i; __builtin_memcpy(&i, &f, 4); unsigned int r = (i + 0x7fffu + ((i >> 16) & 1u)) >> 16; return (u16)r; }
__device__ inline float frcp(float x){ return __builtin_amdgcn_rcpf(x); }
__device__ inline float fsigm(float x){ return frcp(1.f + __expf(-x)); }
__device__ inline float ftanh(float x){ return 2.f * frcp(1.f + __expf(-2.f * x)) - 1.f; }

// ---------------------------------------------------------------- prep: weight casts/transposes + ent cast + bias concat
//  + composed rel-map weight (Wcomb = W_map2@W_map1, bcomb = W_map2@b_map1 + b_map2) + edge histogram
__global__ __launch_bounds__(256) void prep_k(
    const float* __restrict__ Wn, const float* __restrict__ Wl, const float* __restrict__ We,
    const float* __restrict__ wih, const float* __restrict__ whh,
    const float* __restrict__ m1, const float* __restrict__ m2,
    const float* __restrict__ h1, const float* __restrict__ h2,
    const float* __restrict__ attn, const float* __restrict__ alg, const float* __restrict__ rel,
    const float* __restrict__ ent, const float* __restrict__ bat, const float* __restrict__ bh1,
    const float* __restrict__ bm1, const float* __restrict__ bm2,
    const int* __restrict__ edst, int E,
    u16* __restrict__ Bcat, u16* __restrict__ wihb, u16* __restrict__ whhb,
    u16* __restrict__ m1b, u16* __restrict__ m2b, u16* __restrict__ h1b, u16* __restrict__ h2b,
    u16* __restrict__ attnb, u16* __restrict__ algb, u16* __restrict__ relb,
    u16* __restrict__ entb, float* __restrict__ bias2,
    u16* __restrict__ wcb, float* __restrict__ bcombf, int* __restrict__ hist)
{
    int id = blockIdx.x * 256 + threadIdx.x;
    if (id < 49152) { // Bcat[n*384+k] : n in [0,128), k in [0,384)
        int n = id / 384, k = id % 384;
        float v = (k < 128) ? Wn[k*128 + n] : (k < 256 ? Wl[(k-128)*128 + n] : We[(k-256)*128 + n]);
        Bcat[id] = f2bf(v); return;
    }
    id -= 49152;
    if (id < 49152) { wihb[id] = f2bf(wih[id]); return; } id -= 49152;
    if (id < 49152) { whhb[id] = f2bf(whh[id]); return; } id -= 49152;
    if (id < 32768) { m1b[id]  = f2bf(m1[id]);  return; } id -= 32768;
    if (id < 32768) { m2b[id]  = f2bf(m2[id]);  return; } id -= 32768;
    if (id < 16384) { h1b[id]  = f2bf(h1[id]);  return; } id -= 16384;
    if (id < 16384) { h2b[id]  = f2bf(h2[id]);  return; } id -= 16384;
    if (id < 16384) { attnb[id]= f2bf(attn[id]);return; } id -= 16384;
    if (id < 16384) { algb[id] = f2bf(alg[id]); return; } id -= 16384;
    if (id < 58880) { relb[id] = f2bf(rel[id]); return; } id -= 58880;
    if (id < 2560000) { entb[id] = f2bf(ent[id]); return; } id -= 2560000;
    if (id < 256) { bias2[id] = (id < 128) ? bat[id] : bh1[id - 128]; return; } id -= 256;
    if (id < 16384) { // Wcomb[n][j] = sum_k W2[n][k]*W1[k][j]  (f32 compose, bf16 store)
        int n = id >> 7, j = id & 127;
        const float* w2r = m2 + n * 256;
        float s = 0.f;
        for (int k = 0; k < 256; ++k) s += w2r[k] * m1[k*128 + j];
        wcb[id] = f2bf(s); return;
    } id -= 16384;
    if (id < 128) { // bcomb[n] = b2[n] + sum_k W2[n][k]*b1[k]
        const float* w2r = m2 + id * 256;
        float s = bm2[id];
        for (int k = 0; k < 256; ++k) s += w2r[k] * bm1[k];
        bcombf[id] = s; return;
    } id -= 128;
    if (id < E) atomicAdd(&hist[edst[id]], 1);
}

// ---------------------------------------------------------------- exclusive scan over 20000 bins (1 block)
__global__ __launch_bounds__(1024) void scan_k(
    const int* __restrict__ hist, int* __restrict__ starts, int* __restrict__ cursor)
{
    __shared__ int part[1024];
    int t = threadIdx.x;
    int base = t * 20;
    int s = 0;
    for (int j = 0; j < 20; ++j) { int idx = base + j; if (idx < 20000) s += hist[idx]; }
    part[t] = s;
    __syncthreads();
    for (int off = 1; off < 1024; off <<= 1) {
        int v = (t >= off) ? part[t - off] : 0;
        __syncthreads();
        part[t] += v;
        __syncthreads();
    }
    int run = (t > 0) ? part[t - 1] : 0;
    for (int j = 0; j < 20; ++j) {
        int idx = base + j;
        if (idx < 20000) { starts[idx] = run; cursor[idx] = run; run += hist[idx]; }
    }
    if (t == 1023) starts[20000] = run;
}

// ---------------------------------------------------------------- co-dispatch: scatter edges (blocks < eb) | single-stage rel map (8 blocks)
// NO LDS anywhere -> scatter blocks get full residency
__global__ __launch_bounds__(256) void scmap_k(
    const int* __restrict__ src, const int* __restrict__ dst, const int* __restrict__ typ,
    int* __restrict__ cursor, int2* __restrict__ spack, int E, int eb,
    const u16* __restrict__ relb, const u16* __restrict__ wcb, const float* __restrict__ bcombf,
    u16* __restrict__ mapb, u16* __restrict__ mapT)
{
    int tid = threadIdx.x;
    if ((int)blockIdx.x < eb) {
        int e = blockIdx.x * 256 + tid;
        if (e >= E) return;
        int d = dst[e];
        int p = atomicAdd(&cursor[d], 1);
        spack[p] = make_int2(src[e], typ[e]);
        return;
    }
    // ---- single-stage rel map: mapped_rel = rel @ Wcomb^T + bcomb  (+ mapT)
    int wave = tid >> 6, lane = tid & 63;
    int ln = lane & 15, q = lane >> 4;
    int base = (blockIdx.x - eb) * 64 + wave * 16;
    int arow = base + ln; if (arow > 459) arow = 459;
    const u16* Ap = relb + arow * 128;
    f4v acc[8] = {};
    for (int kc = 0; kc < 128; kc += 32) {
        bf8v af = *(const bf8v*)(Ap + kc + q*8);
#pragma unroll
        for (int nt = 0; nt < 8; ++nt) {
            bf8v bv = *(const bf8v*)(wcb + (nt*16 + ln)*128 + kc + q*8);
            acc[nt] = __builtin_amdgcn_mfma_f32_16x16x32_bf16(af, bv, acc[nt], 0, 0, 0);
        }
    }
#pragma unroll
    for (int nt = 0; nt < 8; ++nt) {
        int n = nt*16 + ln;
        float bv = bcombf[n];
#pragma unroll
        for (int r = 0; r < 4; ++r) {
            int m = base + q*4 + r;
            if (m < 460) {
                u16 hv = f2bf(acc[nt][r] + bv);
                mapb[m*128 + n] = hv;
                mapT[n*480 + m] = hv;
            }
        }
    }
}

// ---------------------------------------------------------------- agg gather ONLY: 5000 blocks x 4 independent waves, one wave/entity,
// no LDS, no barrier, minimal VGPR -> max residency for latency hiding
__global__ __launch_bounds__(256) void agg_k(
    const int2* __restrict__ spack, const int* __restrict__ starts,
    const u32* __restrict__ hb, const u32* __restrict__ rb, u32* __restrict__ Acat32)
{
    int tid = threadIdx.x;
    int wave = tid >> 6, lane = tid & 63;
    int i = blockIdx.x * 4 + wave;
    int s0 = starts[i], s1 = starts[i + 1];
    float sx = 0.f, sy = 0.f;
    int e = s0;
    for (; e + 4 <= s1; e += 4) {
        int2 st0 = spack[e], st1 = spack[e+1], st2 = spack[e+2], st3 = spack[e+3];
        u32 a0 = hb[(long)st0.x * 64 + lane]; u32 r0 = rb[(long)st0.y * 64 + lane];
        u32 a1 = hb[(long)st1.x * 64 + lane]; u32 r1 = rb[(long)st1.y * 64 + lane];
        u32 a2 = hb[(long)st2.x * 64 + lane]; u32 r2 = rb[(long)st2.y * 64 + lane];
        u32 a3 = hb[(long)st3.x * 64 + lane]; u32 r3 = rb[(long)st3.y * 64 + lane];
        sx += bf2f((u16)(a0 & 0xffff)) + bf2f((u16)(r0 & 0xffff));
        sy += bf2f((u16)(a0 >> 16))    + bf2f((u16)(r0 >> 16));
        sx += bf2f((u16)(a1 & 0xffff)) + bf2f((u16)(r1 & 0xffff));
        sy += bf2f((u16)(a1 >> 16))    + bf2f((u16)(r1 >> 16));
        sx += bf2f((u16)(a2 & 0xffff)) + bf2f((u16)(r2 & 0xffff));
        sy += bf2f((u16)(a2 >> 16))    + bf2f((u16)(r2 >> 16));
        sx += bf2f((u16)(a3 & 0xffff)) + bf2f((u16)(r3 & 0xffff));
        sy += bf2f((u16)(a3 >> 16))    + bf2f((u16)(r3 >> 16));
    }
    for (; e < s1; ++e) {
        int2 st = spack[e];
        u32 a = hb[(long)st.x * 64 + lane];
        u32 r = rb[(long)st.y * 64 + lane];
        sx += bf2f((u16)(a & 0xffff)) + bf2f((u16)(r & 0xffff));
        sy += bf2f((u16)(a >> 16))    + bf2f((u16)(r >> 16));
    }
    bool has = s1 > s0;
    float nrm = has ? frcp((float)(s1 - s0)) : 0.f;
    u32 hv = hb[(long)i * 64 + lane];
    u32 agg = (u32)f2bf(sx * nrm) | ((u32)f2bf(sy * nrm) << 16);
    long o = (long)i * 192 + lane;
    Acat32[o]       = agg;
    Acat32[o + 64]  = has ? hv : 0u;
    Acat32[o + 128] = has ? 0u : hv;
}

// ---------------------------------------------------------------- co-dispatch: [pre_emb+aligned fused, 313 blocks] | [q_rel->attnq/th1->pred, 16 blocks]
__global__ __launch_bounds__(256) void prealnq_k(
    const u16* __restrict__ acat, const u16* __restrict__ bcat,
    const u16* __restrict__ alb, const float* __restrict__ bal,
    u16* __restrict__ preb, u16* __restrict__ alnb,
    const u16* __restrict__ mapb, const int* __restrict__ trip,
    const u16* __restrict__ atb, const float* __restrict__ bias2,
    const u16* __restrict__ h2b, const float* __restrict__ bh2,
    u16* __restrict__ atq, float* __restrict__ pred, u16* __restrict__ X)
{
    __shared__ u16 lds[4][16][136];    // pl (prealn) / th1l (qt) union
    int tid = threadIdx.x;
    int wave = tid >> 6, lane = tid & 63;
    int ln = lane & 15, q = lane >> 4;
    if (blockIdx.x < 313) {
        // ---- prealn branch: pre = rrelu(acat@Bcat^T) -> aligned = pre@W_align^T + b
        int bm = blockIdx.x * 64 + wave * 16;
        int am = bm + ln; if (am > 19999) am = 19999;
        const u16* Ap = acat + (long)am * 384;
        f4v acc[8] = {};
        for (int kc = 0; kc < 384; kc += 32) {
            bf8v af = *(const bf8v*)(Ap + kc + q*8);
#pragma unroll
            for (int nt = 0; nt < 8; ++nt) {
                bf8v bv = *(const bf8v*)(bcat + (nt*16 + ln)*384 + kc + q*8);
                acc[nt] = __builtin_amdgcn_mfma_f32_16x16x32_bf16(af, bv, acc[nt], 0, 0, 0);
            }
        }
#pragma unroll
        for (int nt = 0; nt < 8; ++nt) {
            int n = nt*16 + ln;
#pragma unroll
            for (int r = 0; r < 4; ++r) {
                int m = bm + q*4 + r;
                float v = acc[nt][r];
                v = (v >= 0.f) ? v : v * RRELU_SLOPE;
                u16 hv = f2bf(v);
                lds[wave][q*4 + r][n] = hv;
                if (m < 20000) preb[(long)m*128 + n] = hv;
            }
        }
        // wave-private staging: no block barrier needed
        f4v acc2[8] = {};
        for (int kc = 0; kc < 128; kc += 32) {
            bf8v af = *(const bf8v*)&lds[wave][ln][kc + q*8];
#pragma unroll
            for (int nt = 0; nt < 8; ++nt) {
                bf8v bv = *(const bf8v*)(alb + (nt*16 + ln)*128 + kc + q*8);
                acc2[nt] = __builtin_amdgcn_mfma_f32_16x16x32_bf16(af, bv, acc2[nt], 0, 0, 0);
            }
        }
#pragma unroll
        for (int nt = 0; nt < 8; ++nt) {
            int n = nt*16 + ln;
            float bv = bal[n];
#pragma unroll
            for (int r = 0; r < 4; ++r) {
                int m = bm + q*4 + r;
                if (m < 20000) alnb[(long)m*128 + n] = f2bf(acc2[nt][r] + bv);
            }
        }
        return;
    }
    // ---- qt branch: q_rel gather -> [attnq | th1] -> pred (+ X tail rows)
    int base = (blockIdx.x - 313) * 64 + wave * 16;
    int ar = trip[(base + ln)*3 + 1];
    const u16* Ap = mapb + ar * 128;
    int rm_[4];
#pragma unroll
    for (int r = 0; r < 4; ++r) rm_[r] = trip[(base + q*4 + r)*3 + 1];
    f4v acc1[16] = {};
    for (int kc = 0; kc < 128; kc += 32) {
        bf8v af = *(const bf8v*)(Ap + kc + q*8);
#pragma unroll
        for (int nt = 0; nt < 16; ++nt) {
            bf8v bv = *(const bf8v*)(atb + (nt*16 + ln)*128 + kc + q*8);
            acc1[nt] = __builtin_amdgcn_mfma_f32_16x16x32_bf16(af, bv, acc1[nt], 0, 0, 0);
        }
    }
#pragma unroll
    for (int nt = 0; nt < 16; ++nt) {
        int n = nt*16 + ln;
        float bv = bias2[n];
#pragma unroll
        for (int r = 0; r < 4; ++r) {
            int m = base + q*4 + r;
            float x = acc1[nt][r] + bv;
            if (nt < 8) {
                atq[m*128 + n] = f2bf(x);
                X[(long)(8192 + m)*128 + n] = mapb[rm_[r]*128 + n];  // X tail = q_rel
            } else lds[wave][q*4 + r][n - 128] = f2bf(x);
        }
    }
    // wave-private staging: no block barrier needed
    f4v acc2[8] = {};
    for (int kc = 0; kc < 128; kc += 32) {
        bf8v af = *(const bf8v*)&lds[wave][ln][kc + q*8];
#pragma unroll
        for (int nt = 0; nt < 8; ++nt) {
            bf8v bv = *(const bf8v*)(h2b + (nt*16 + ln)*128 + kc + q*8);
            acc2[nt] = __builtin_amdgcn_mfma_f32_16x16x32_bf16(af, bv, acc2[nt], 0, 0, 0);
        }
    }
#pragma unroll
    for (int nt = 0; nt < 8; ++nt) {
        int n = nt*16 + ln;
        float bv = bh2[n];
#pragma unroll
        for (int r = 0; r < 4; ++r) {
            int m = base + q*4 + r;
            pred[(long)m*128 + n] = 0.1f * (acc2[nt][r] + bv) + bf2f(mapb[rm_[r]*128 + n]);
        }
    }
}

// ---------------------------------------------------------------- fused A-rows + masked-softmax(460) + rel_path GEMM (K=480)
// block = 4 batch rows x 8 timesteps; A rows computed in-kernel via replicated-row MFMA
__global__ __launch_bounds__(256) void smrp_k(
    const u16* __restrict__ atq, const u16* __restrict__ mapb,
    const float* __restrict__ part, const u16* __restrict__ mapT, u16* __restrict__ X)
{
    __shared__ u16 xls[32][488];
    __shared__ float asl[4][464];
    int tid = threadIdx.x;
    int wave = tid >> 6, lane = tid & 63;
    int ln = lane & 15, q = lane >> 4;
    int b0 = blockIdx.x * 4;           // 256 blocks x 4 batch rows
    // A[db][n] = atq[b0+db] @ mapped_rel^T  (29 n-tiles strided over waves)
    {
        const u16* Ap = atq + (long)(b0 + (ln & 3)) * 128;
        bf8v af[4];
#pragma unroll
        for (int kc = 0; kc < 4; ++kc) af[kc] = *(const bf8v*)(Ap + kc*32 + q*8);
        for (int nt = wave; nt < 29; nt += 4) {
            int brow = nt*16 + ln; if (brow > 459) brow = 459;
            f4v acc = {};
#pragma unroll
            for (int kc = 0; kc < 4; ++kc) {
                bf8v bv = *(const bf8v*)(mapb + (long)brow*128 + kc*32 + q*8);
                acc = __builtin_amdgcn_mfma_f32_16x16x32_bf16(af[kc], bv, acc, 0, 0, 0);
            }
            if (q == 0) {
                int n = nt*16 + ln;
                if (n < 460) {
#pragma unroll
                    for (int r = 0; r < 4; ++r) asl[r][n] = acc[r];
                }
            }
        }
    }
    __syncthreads();
    for (int j = 0; j < 8; ++j) {
        int rl = wave*8 + j;           // rl = t*4 + db
        int t = rl >> 2, db = rl & 3;
        const float* crow = part + (long)(b0 + db)*3680 + t*460;
        float v[8], e[8];
        float m = -1e30f;
#pragma unroll
        for (int i = 0; i < 8; ++i) {
            int r = i*64 + lane;
            if (r < 460) {
                float x = crow[r] * asl[db][r];
                x = (x == 0.f) ? -1e9f : x;
                v[i] = x; m = fmaxf(m, x);
            } else v[i] = -1e30f;
        }
#pragma unroll
        for (int off = 32; off; off >>= 1) m = fmaxf(m, __shfl_xor(m, off));
        float sum = 0.f;
#pragma unroll
        for (int i = 0; i < 8; ++i) {
            int r = i*64 + lane;
            e[i] = 0.f;
            if (r < 460) { e[i] = __expf(v[i] - m); sum += e[i]; }
        }
#pragma unroll
        for (int off = 32; off; off >>= 1) sum += __shfl_xor(sum, off);
        float inv = frcp(sum);
#pragma unroll
        for (int i = 0; i < 8; ++i) {
            int r = i*64 + lane;
            if (r < 460)      xls[rl][r] = f2bf(e[i] * inv);
            else if (r < 488) xls[rl][r] = 0;
        }
    }
    __syncthreads();
    f4v acc[2][2] = {};
    for (int kc = 0; kc < 480; kc += 32) {
        bf8v a[2], bfr[2];
#pragma unroll
        for (int mt = 0; mt < 2; ++mt)
            a[mt] = *(const bf8v*)&xls[mt*16 + ln][kc + q*8];
#pragma unroll
        for (int nt = 0; nt < 2; ++nt)
            bfr[nt] = *(const bf8v*)(mapT + (wave*32 + nt*16 + ln)*480 + kc + q*8);
#pragma unroll
        for (int mt = 0; mt < 2; ++mt)
#pragma unroll
            for (int nt = 0; nt < 2; ++nt)
                acc[mt][nt] = __builtin_amdgcn_mfma_f32_16x16x32_bf16(a[mt], bfr[nt], acc[mt][nt], 0, 0, 0);
    }
#pragma unroll
    for (int mt = 0; mt < 2; ++mt)
#pragma unroll
    for (int nt = 0; nt < 2; ++nt) {
        int n = wave*32 + nt*16 + ln;
#pragma unroll
        for (int r = 0; r < 4; ++r) {
            int rl = mt*16 + q*4 + r;
            long m = (long)(rl >> 2)*1024 + b0 + (rl & 3);
            X[m*128 + n] = f2bf(acc[mt][nt][r]);
        }
    }
}

// ---------------------------------------------------------------- GRU scan: fused gi = X@wih^T, fused SubL prologue, fused V/obj epilogue
__global__ __launch_bounds__(256, 1) void gru_k(
    const u16* __restrict__ X, const u16* __restrict__ wihb, const float* __restrict__ bih,
    const u16* __restrict__ whhb, const float* __restrict__ bhh,
    const float* __restrict__ pred,
    const u16* __restrict__ preb, const u16* __restrict__ alb, const float* __restrict__ bal,
    const u16* __restrict__ AL, const int* __restrict__ trip,
    u16* __restrict__ V, float* __restrict__ accp)
{
    __shared__ u16  hbf[16][136];   // rows 4..15 stay zero
    __shared__ float hf [4][128];
    __shared__ float ghl[4][388];
    __shared__ float gil[4][388];
    __shared__ float sll[4][132];
    __shared__ float redm[4], redo[4];
    int tid = threadIdx.x;
    int wave = tid >> 6, lane = tid & 63;
    int ln = lane & 15, q = lane >> 4;
    int bb = blockIdx.x * 4;
    for (int i = tid; i < 16*136; i += 256) hbf[i/136][i%136] = 0;
    for (int i = tid; i < 4*128; i += 256) hf[i>>7][i&127] = 0.f;
    // preload whh + wih fragments: 6 N-tiles x 4 K-chunks per wave each (192 VGPRs; 1 blk/CU anyway)
    bf8v bfrag[6][4], wfrag[6][4];
#pragma unroll
    for (int nt = 0; nt < 6; ++nt)
#pragma unroll
        for (int kc = 0; kc < 4; ++kc) {
            bfrag[nt][kc] = *(const bf8v*)(whhb + (long)(wave*96 + nt*16 + ln)*128 + kc*32 + q*8);
            wfrag[nt][kc] = *(const bf8v*)(wihb + (long)(wave*96 + nt*16 + ln)*128 + kc*32 + q*8);
        }
    // SubL = pre_emb[trip[:,0]] @ W_align^T + b_align for this block's 4 rows
    {
        const u16* Pp = preb + (long)trip[(bb + (ln & 3))*3 + 0] * 128;
        f4v sacc[2] = {};
#pragma unroll
        for (int kc = 0; kc < 4; ++kc) {
            bf8v pf = *(const bf8v*)(Pp + kc*32 + q*8);
#pragma unroll
            for (int nt = 0; nt < 2; ++nt) {
                bf8v bv = *(const bf8v*)(alb + (long)(wave*32 + nt*16 + ln)*128 + kc*32 + q*8);
                sacc[nt] = __builtin_amdgcn_mfma_f32_16x16x32_bf16(pf, bv, sacc[nt], 0, 0, 0);
            }
        }
        if (q == 0) {
#pragma unroll
            for (int nt = 0; nt < 2; ++nt) {
                int n = wave*32 + nt*16 + ln;
                float bv = bal[n];
#pragma unroll
                for (int r = 0; r < 4; ++r) sll[r][n] = sacc[nt][r] + bv;
            }
        }
    }
    int k = tid & 127;
    float cr = bih[k] + bhh[k];
    float cz = bih[128 + k] + bhh[128 + k];
    float bin_ = bih[256 + k], bhn = bhh[256 + k];
    __syncthreads();
    float msum = 0.f, osum = 0.f;
    for (int t = 0; t <= 8; ++t) {
        float pv[2];
#pragma unroll
        for (int it = 0; it < 2; ++it) {
            int m = it*2 + (tid >> 7);
            pv[it] = (t >= 7) ? pred[(long)(bb + m)*128 + k] : 0.f;
        }
        if (t == 8) {
#pragma unroll
            for (int it = 0; it < 2; ++it) {
                int m = it*2 + (tid >> 7);
                hf[m][k] = pv[it]; hbf[m][k] = f2bf(pv[it]);
            }
            __syncthreads();
        }
        // gi = x_t @ wih^T (rows from X, 4-way replicated across lanes) ; gh = h @ whh^T
        long xr0 = (t < 8) ? ((long)t*1024 + bb) : (long)(8192 + bb);
        const u16* Xp = X + (xr0 + (ln & 3))*128;
        f4v gacc[6] = {};
        f4v acc[6] = {};
#pragma unroll
        for (int kc = 0; kc < 4; ++kc) {
            bf8v xf = *(const bf8v*)(Xp + kc*32 + q*8);
            bf8v af = *(const bf8v*)&hbf[ln][kc*32 + q*8];
#pragma unroll
            for (int nt = 0; nt < 6; ++nt) {
                gacc[nt] = __builtin_amdgcn_mfma_f32_16x16x32_bf16(xf, wfrag[nt][kc], gacc[nt], 0, 0, 0);
                acc[nt]  = __builtin_amdgcn_mfma_f32_16x16x32_bf16(af, bfrag[nt][kc], acc[nt],  0, 0, 0);
            }
        }
        if (q == 0) {
#pragma unroll
            for (int nt = 0; nt < 6; ++nt)
#pragma unroll
                for (int r = 0; r < 4; ++r) {
                    ghl[r][wave*96 + nt*16 + ln] = acc[nt][r];
                    gil[r][wave*96 + nt*16 + ln] = gacc[nt][r];
                }
        }
        __syncthreads();
#pragma unroll
        for (int it = 0; it < 2; ++it) {
            int m = it*2 + (tid >> 7);
            float rr = fsigm(gil[m][k] + ghl[m][k] + cr);
            float zz = fsigm(gil[m][128 + k] + ghl[m][128 + k] + cz);
            float nn = ftanh(gil[m][256 + k] + bin_ + rr * (ghl[m][256 + k] + bhn));
            float hn = (1.f - zz) * nn + zz * hf[m][k];
            if (t == 7) { float d = pv[it] - hn; msum += d*d; }
            if (t == 8) {
                u16 vb = f2bf(sll[m][k] * hn);
                V[(long)(bb + m)*128 + k] = vb;
                int obj = trip[(bb + m)*3 + 2];
                osum += bf2f(vb) * bf2f(AL[(long)obj*128 + k]);
            } else { hf[m][k] = hn; hbf[m][k] = f2bf(hn); }
        }
        __syncthreads();
    }
#pragma unroll
    for (int off = 32; off; off >>= 1) { msum += __shfl_down(msum, off); osum += __shfl_down(osum, off); }
    if (lane == 0) { redm[wave] = msum; redo[wave] = osum; }
    __syncthreads();
    if (tid == 0) {
        atomicAdd(accp + 0, redm[0] + redm[1] + redm[2] + redm[3]);
        atomicAdd(accp + 2, -(redo[0] + redo[1] + redo[2] + redo[3]));
    }
}

// ---------------------------------------------------------------- score GEMM: 8 waves x (64x32)/wave, half-tile LDS staging,
// full-line nt stores; grid (8,157): consecutive blocks share the AL column strip for L2 reuse.
// e = exp(-|s|), d = 1+e:  sigma = (s>=0 ? 1 : e)/d ;  softplus(s) = max(s,0) + log(d)
__global__ __launch_bounds__(512) void score_k(
    const u16* __restrict__ V, const u16* __restrict__ AL,
    float* __restrict__ out, float* __restrict__ sp_acc, int N)
{
    __shared__ float stage[8][1024];   // 32 rows x 32 cols f32 per wave (wave-private)
    int tid = threadIdx.x;
    int wave = tid >> 6, lane = tid & 63;
    int ln = lane & 15, q = lane >> 4;
    int bm = blockIdx.x * 128 + (wave >> 2) * 64;
    int bn = blockIdx.y * 128 + (wave & 3) * 32;
    bool valid = bn < N;               // N % 32 == 0 -> whole 32-col strip valid or not
    int br[2];
#pragma unroll
    for (int nt = 0; nt < 2; ++nt) { int n = bn + nt*16 + ln; br[nt] = (n < N) ? n : (N - 1); }
    f4v acc[4][2] = {};
    for (int kc = 0; kc < 128; kc += 32) {
        bf8v a[4], b[2];
#pragma unroll
        for (int mt = 0; mt < 4; ++mt)
            a[mt] = *(const bf8v*)(V + (long)(bm + mt*16 + ln)*128 + kc + q*8);
#pragma unroll
        for (int nt = 0; nt < 2; ++nt)
            b[nt] = *(const bf8v*)(AL + (long)br[nt]*128 + kc + q*8);
#pragma unroll
        for (int mt = 0; mt < 4; ++mt)
#pragma unroll
            for (int nt = 0; nt < 2; ++nt)
                acc[mt][nt] = __builtin_amdgcn_mfma_f32_16x16x32_bf16(a[mt], b[nt], acc[mt][nt], 0, 0, 0);
    }
    float lsum = 0.f;
    float* st = stage[wave];
#pragma unroll
    for (int half = 0; half < 2; ++half) {
#pragma unroll
        for (int mh = 0; mh < 2; ++mh) {
            int mt = half*2 + mh;
#pragma unroll
            for (int nt = 0; nt < 2; ++nt)
#pragma unroll
            for (int r = 0; r < 4; ++r) {
                float s = acc[mt][nt][r];
                float e = __expf(-fabsf(s));
                float d = 1.f + e;
                float inv = frcp(d);
                st[(mh*16 + q*4 + r)*32 + nt*16 + ln] = (s >= 0.f) ? inv : e * inv;
                lsum += fmaxf(s, 0.f) + __logf(d);
            }
        }
        // wave-private LDS: no block barrier needed; write full 128B lines
        if (valid) {
            int row0 = lane >> 3, c4 = (lane & 7) << 2;
#pragma unroll
            for (int i = 0; i < 4; ++i) {
                int row = i*8 + row0;
                f4v vv = *(const f4v*)&st[row*32 + c4];
                __builtin_nontemporal_store(vv, (f4v*)&out[(long)(bm + half*32 + row)*N + bn + c4]);
            }
        }
    }
    if (!valid) lsum = 0.f;
#pragma unroll
    for (int off = 32; off; off >>= 1) lsum += __shfl_xor(lsum, off);
    __shared__ float red[8];
    if (lane == 0) red[wave] = lsum;
    __syncthreads();
    if (tid == 0) {
        float tsum = 0.f;
#pragma unroll
        for (int w = 0; w < 8; ++w) tsum += red[w];
        atomicAdd(sp_acc, tsum);
    }
}

// ---------------------------------------------------------------- finalize scalars
__global__ void final_k(const float* __restrict__ acc, float* __restrict__ out)
{
    out[20480000] = acc[0] / (1024.f * 128.f);
    out[20480001] = (acc[1] + acc[2]) / (1024.f * 20000.f);
}

// ================================================================ host
extern "C" void kernel_launch(void* const* d_in, const int* in_sizes, int n_in,
                              void* d_out, int out_size, void* d_ws, size_t ws_size,
                              hipStream_t stream)
{
    const float* ent  = (const float*)d_in[0];
    const float* rel  = (const float*)d_in[1];
    const float* Wn   = (const float*)d_in[2];
    const float* Wl   = (const float*)d_in[3];
    const float* We   = (const float*)d_in[4];
    const float* wih  = (const float*)d_in[5];
    const float* whh  = (const float*)d_in[6];
    const float* b_ih = (const float*)d_in[7];
    const float* b_hh = (const float*)d_in[8];
    const float* Wm1  = (const float*)d_in[9];
    const float* bm1  = (const float*)d_in[10];
    const float* Wm2  = (const float*)d_in[11];
    const float* bm2  = (const float*)d_in[12];
    const float* Wh1  = (const float*)d_in[13];
    const float* bh1  = (const float*)d_in[14];
    const float* Wh2  = (const float*)d_in[15];
    const float* bh2  = (const float*)d_in[16];
    const float* Wal  = (const float*)d_in[17];
    const float* bal  = (const float*)d_in[18];
    const float* Wat  = (const float*)d_in[19];
    const float* bat  = (const float*)d_in[20];
    const float* part = (const float*)d_in[21];
    const int* esrc   = (const int*)d_in[22];
    const int* edst   = (const int*)d_in[23];
    const int* etyp   = (const int*)d_in[24];
    const int* trip   = (const int*)d_in[25];
    float* out = (float*)d_out;
    const int E = in_sizes[22];

    char* ws = (char*)d_ws;
    size_t off = 0;
    auto alloc = [&](size_t bytes) { size_t o = off; off = (off + bytes + 255) & ~(size_t)255; return o; };

    // zeroed region first (one memset)
    size_t o_acc   = alloc(256);                  // [0]=match [1]=softplus [2]=obj
    size_t o_hist  = alloc(20000 * 4);
    size_t o_mapT  = alloc(128 * 480 * 2);
    size_t zend = off;
    // non-zeroed
    size_t o_starts= alloc(20004 * 4);
    size_t o_cur   = alloc(20000 * 4);
    size_t o_spack = alloc((size_t)E * 8);
    size_t o_entb  = alloc((size_t)20000 * 128 * 2);
    size_t o_acat  = alloc((size_t)20000 * 384 * 2);
    size_t o_pre   = alloc((size_t)20000 * 128 * 2);
    size_t o_aln   = alloc((size_t)20000 * 128 * 2);
    size_t o_bcat  = alloc(128 * 384 * 2);
    size_t o_wih   = alloc(384 * 128 * 2);
    size_t o_whh   = alloc(384 * 128 * 2);
    size_t o_m1    = alloc(256 * 128 * 2);
    size_t o_m2    = alloc(128 * 256 * 2);
    size_t o_ath   = alloc(2 * 128 * 128 * 2);    // [W_attn ; W_h1] adjacent (N=256 stage-1)
    size_t o_h2    = alloc(128 * 128 * 2);
    size_t o_al    = alloc(128 * 128 * 2);
    size_t o_rel   = alloc(460 * 128 * 2);
    size_t o_map   = alloc(460 * 128 * 2);
    size_t o_wcb   = alloc(128 * 128 * 2);        // composed rel-map weight (bf16)
    size_t o_bcf   = alloc(128 * 4);              // composed rel-map bias (f32)
    size_t o_atq   = alloc(1024 * 128 * 2);
    size_t o_b2    = alloc(256 * 4);              // [b_attn ; b_h1]
    size_t o_pred  = alloc(1024 * 128 * 4);
    size_t o_X     = alloc((size_t)9216 * 128 * 2);
    size_t o_V     = alloc(1024 * 128 * 2);

    float* accp  = (float*)(ws + o_acc);
    int* histp   = (int*)(ws + o_hist);
    u16* mapT    = (u16*)(ws + o_mapT);
    int* startsp = (int*)(ws + o_starts);
    int* curp    = (int*)(ws + o_cur);
    int2* spack  = (int2*)(ws + o_spack);
    u16* entb    = (u16*)(ws + o_entb);
    u16* acat    = (u16*)(ws + o_acat);
    u16* preb    = (u16*)(ws + o_pre);
    u16* alnb    = (u16*)(ws + o_aln);
    u16* bcat    = (u16*)(ws + o_bcat);
    u16* wihb    = (u16*)(ws + o_wih);
    u16* whhb    = (u16*)(ws + o_whh);
    u16* m1b     = (u16*)(ws + o_m1);
    u16* m2b     = (u16*)(ws + o_m2);
    u16* atb     = (u16*)(ws + o_ath);
    u16* h1b     = atb + 128 * 128;
    u16* h2b     = (u16*)(ws + o_h2);
    u16* alb     = (u16*)(ws + o_al);
    u16* relb    = (u16*)(ws + o_rel);
    u16* mapb    = (u16*)(ws + o_map);
    u16* wcb     = (u16*)(ws + o_wcb);
    float* bcombf= (float*)(ws + o_bcf);
    u16* atqb    = (u16*)(ws + o_atq);
    float* bias2 = (float*)(ws + o_b2);
    float* predf = (float*)(ws + o_pred);
    u16* Xb      = (u16*)(ws + o_X);
    u16* Vb      = (u16*)(ws + o_V);

    hipMemsetAsync(ws, 0, zend, stream);

    // prep covers: weights (337408) + ent cast (2560000) + bias concat (256)
    //            + Wcomb (16384) + bcomb (128) + edge histogram (E)
    int ptot = 2914176 + E;
    prep_k<<<(ptot + 255) / 256, 256, 0, stream>>>(
        Wn, Wl, We, wih, whh, Wm1, Wm2, Wh1, Wh2, Wat, Wal, rel,
        ent, bat, bh1, bm1, bm2, edst, E,
        bcat, wihb, whhb, m1b, m2b, h1b, h2b, atb, alb, relb,
        entb, bias2, wcb, bcombf, histp);

    scan_k<<<1, 1024, 0, stream>>>(histp, startsp, curp);

    // co-dispatch: scatter (eb blocks) | single-stage rel-map (8 blocks) — zero LDS
    int eb = (E + 255) / 256;
    scmap_k<<<eb + 8, 256, 0, stream>>>(esrc, edst, etyp, curp, spack, E, eb,
                                        relb, wcb, bcombf, mapb, mapT);

    // agg gather only: 5000 blocks x 4 independent waves, minimal footprint
    agg_k<<<5000, 256, 0, stream>>>(spack, startsp, (const u32*)entb, (const u32*)relb, (u32*)acat);

    // co-dispatch: pre_emb+aligned fused (313 blocks) | q_rel->attnq/th1->pred (16 blocks)
    prealnq_k<<<329, 256, 0, stream>>>(acat, bcat, alb, bal, preb, alnb,
                                       mapb, trip, atb, bias2, h2b, bh2, atqb, predf, Xb);

    // A-rows + softmax + rel_path fused -> X rows 0..8191 (bf16)
    smrp_k<<<256, 256, 0, stream>>>(atqb, mapb, part, mapT, Xb);

    // GRU scan with fused gi-GEMM, SubL prologue, V/obj epilogue
    gru_k<<<256, 256, 0, stream>>>(Xb, wihb, b_ih, whhb, b_hh, predf, preb, alb, bal, alnb, trip, Vb, accp);

    // score + softplus reduce  (grid: row-tiles fastest -> AL strip L2 reuse)
    score_k<<<dim3(8, 157), 512, 0, stream>>>(Vb, alnb, out, accp + 1, 20000);

    final_k<<<1, 1, 0, stream>>>(accp, out);

    (void)in_sizes; (void)n_in; (void)out_size; (void)ws_size;
}

// Round 13
// 397.527 us; speedup vs baseline: 1.2083x; 1.0018x over previous
//
#include <hip/hip_runtime.h>

typedef unsigned short u16;
typedef unsigned int u32;
typedef __attribute__((ext_vector_type(8))) short bf8v;
typedef __attribute__((ext_vector_type(4))) float f4v;

#define RRELU_SLOPE 0.22916666667f

__device__ inline float bf2f(u16 u){ unsigned int i = ((unsigned int)u) << 16; float f; __builtin_memcpy(&f, &i, 4); return f; }
__device__ inline u16 f2bf(float f){ unsigned int i; __builtin_memcpy(&i, &f, 4); unsigned int r = (i + 0x7fffu + ((i >> 16) & 1u)) >> 16; return (u16)r; }
__device__ inline float frcp(float x){ return __builtin_amdgcn_rcpf(x); }
__device__ inline float fsigm(float x){ return frcp(1.f + __expf(-x)); }
__device__ inline float ftanh(float x){ return 2.f * frcp(1.f + __expf(-2.f * x)) - 1.f; }

// ---------------------------------------------------------------- prep: weight casts/transposes + ent cast + bias concat
//  + composed rel-map weight (Wcomb = W_map2@W_map1, bcomb = W_map2@b_map1 + b_map2) + edge histogram
__global__ __launch_bounds__(256) void prep_k(
    const float* __restrict__ Wn, const float* __restrict__ Wl, const float* __restrict__ We,
    const float* __restrict__ wih, const float* __restrict__ whh,
    const float* __restrict__ m1, const float* __restrict__ m2,
    const float* __restrict__ h1, const float* __restrict__ h2,
    const float* __restrict__ attn, const float* __restrict__ alg, const float* __restrict__ rel,
    const float* __restrict__ ent, const float* __restrict__ bat, const float* __restrict__ bh1,
    const float* __restrict__ bm1, const float* __restrict__ bm2,
    const int* __restrict__ edst, int E,
    u16* __restrict__ Bcat, u16* __restrict__ wihb, u16* __restrict__ whhb,
    u16* __restrict__ m1b, u16* __restrict__ m2b, u16* __restrict__ h1b, u16* __restrict__ h2b,
    u16* __restrict__ attnb, u16* __restrict__ algb, u16* __restrict__ relb,
    u16* __restrict__ entb, float* __restrict__ bias2,
    u16* __restrict__ wcb, float* __restrict__ bcombf, int* __restrict__ hist)
{
    int id = blockIdx.x * 256 + threadIdx.x;
    if (id < 49152) { // Bcat[n*384+k] : n in [0,128), k in [0,384)
        int n = id / 384, k = id % 384;
        float v = (k < 128) ? Wn[k*128 + n] : (k < 256 ? Wl[(k-128)*128 + n] : We[(k-256)*128 + n]);
        Bcat[id] = f2bf(v); return;
    }
    id -= 49152;
    if (id < 49152) { wihb[id] = f2bf(wih[id]); return; } id -= 49152;
    if (id < 49152) { whhb[id] = f2bf(whh[id]); return; } id -= 49152;
    if (id < 32768) { m1b[id]  = f2bf(m1[id]);  return; } id -= 32768;
    if (id < 32768) { m2b[id]  = f2bf(m2[id]);  return; } id -= 32768;
    if (id < 16384) { h1b[id]  = f2bf(h1[id]);  return; } id -= 16384;
    if (id < 16384) { h2b[id]  = f2bf(h2[id]);  return; } id -= 16384;
    if (id < 16384) { attnb[id]= f2bf(attn[id]);return; } id -= 16384;
    if (id < 16384) { algb[id] = f2bf(alg[id]); return; } id -= 16384;
    if (id < 58880) { relb[id] = f2bf(rel[id]); return; } id -= 58880;
    if (id < 2560000) { entb[id] = f2bf(ent[id]); return; } id -= 2560000;
    if (id < 256) { bias2[id] = (id < 128) ? bat[id] : bh1[id - 128]; return; } id -= 256;
    if (id < 16384) { // Wcomb[n][j] = sum_k W2[n][k]*W1[k][j]  (f32 compose, bf16 store)
        int n = id >> 7, j = id & 127;
        const float* w2r = m2 + n * 256;
        float s = 0.f;
        for (int k = 0; k < 256; ++k) s += w2r[k] * m1[k*128 + j];
        wcb[id] = f2bf(s); return;
    } id -= 16384;
    if (id < 128) { // bcomb[n] = b2[n] + sum_k W2[n][k]*b1[k]
        const float* w2r = m2 + id * 256;
        float s = bm2[id];
        for (int k = 0; k < 256; ++k) s += w2r[k] * bm1[k];
        bcombf[id] = s; return;
    } id -= 128;
    if (id < E) atomicAdd(&hist[edst[id]], 1);
}

// ---------------------------------------------------------------- exclusive scan over 20000 bins (1 block)
__global__ __launch_bounds__(1024) void scan_k(
    const int* __restrict__ hist, int* __restrict__ starts, int* __restrict__ cursor)
{
    __shared__ int part[1024];
    int t = threadIdx.x;
    int base = t * 20;
    int s = 0;
    for (int j = 0; j < 20; ++j) { int idx = base + j; if (idx < 20000) s += hist[idx]; }
    part[t] = s;
    __syncthreads();
    for (int off = 1; off < 1024; off <<= 1) {
        int v = (t >= off) ? part[t - off] : 0;
        __syncthreads();
        part[t] += v;
        __syncthreads();
    }
    int run = (t > 0) ? part[t - 1] : 0;
    for (int j = 0; j < 20; ++j) {
        int idx = base + j;
        if (idx < 20000) { starts[idx] = run; cursor[idx] = run; run += hist[idx]; }
    }
    if (t == 1023) starts[20000] = run;
}

// ---------------------------------------------------------------- co-dispatch: scatter edges (blocks < eb) | single-stage rel map (8 blocks)
// NO LDS anywhere -> scatter blocks get full residency
__global__ __launch_bounds__(256) void scmap_k(
    const int* __restrict__ src, const int* __restrict__ dst, const int* __restrict__ typ,
    int* __restrict__ cursor, int2* __restrict__ spack, int E, int eb,
    const u16* __restrict__ relb, const u16* __restrict__ wcb, const float* __restrict__ bcombf,
    u16* __restrict__ mapb, u16* __restrict__ mapT)
{
    int tid = threadIdx.x;
    if ((int)blockIdx.x < eb) {
        int e = blockIdx.x * 256 + tid;
        if (e >= E) return;
        int d = dst[e];
        int p = atomicAdd(&cursor[d], 1);
        spack[p] = make_int2(src[e], typ[e]);
        return;
    }
    // ---- single-stage rel map: mapped_rel = rel @ Wcomb^T + bcomb  (+ mapT)
    int wave = tid >> 6, lane = tid & 63;
    int ln = lane & 15, q = lane >> 4;
    int base = (blockIdx.x - eb) * 64 + wave * 16;
    int arow = base + ln; if (arow > 459) arow = 459;
    const u16* Ap = relb + arow * 128;
    f4v acc[8] = {};
    for (int kc = 0; kc < 128; kc += 32) {
        bf8v af = *(const bf8v*)(Ap + kc + q*8);
#pragma unroll
        for (int nt = 0; nt < 8; ++nt) {
            bf8v bv = *(const bf8v*)(wcb + (nt*16 + ln)*128 + kc + q*8);
            acc[nt] = __builtin_amdgcn_mfma_f32_16x16x32_bf16(af, bv, acc[nt], 0, 0, 0);
        }
    }
#pragma unroll
    for (int nt = 0; nt < 8; ++nt) {
        int n = nt*16 + ln;
        float bv = bcombf[n];
#pragma unroll
        for (int r = 0; r < 4; ++r) {
            int m = base + q*4 + r;
            if (m < 460) {
                u16 hv = f2bf(acc[nt][r] + bv);
                mapb[m*128 + n] = hv;
                mapT[n*480 + m] = hv;
            }
        }
    }
}

// ---------------------------------------------------------------- agg gather ONLY: 5000 blocks x 4 independent waves, one wave/entity,
// no LDS, no barrier, minimal VGPR -> max residency for latency hiding
__global__ __launch_bounds__(256) void agg_k(
    const int2* __restrict__ spack, const int* __restrict__ starts,
    const u32* __restrict__ hb, const u32* __restrict__ rb, u32* __restrict__ Acat32)
{
    int tid = threadIdx.x;
    int wave = tid >> 6, lane = tid & 63;
    int i = blockIdx.x * 4 + wave;
    int s0 = starts[i], s1 = starts[i + 1];
    float sx = 0.f, sy = 0.f;
    int e = s0;
    for (; e + 4 <= s1; e += 4) {
        int2 st0 = spack[e], st1 = spack[e+1], st2 = spack[e+2], st3 = spack[e+3];
        u32 a0 = hb[(long)st0.x * 64 + lane]; u32 r0 = rb[(long)st0.y * 64 + lane];
        u32 a1 = hb[(long)st1.x * 64 + lane]; u32 r1 = rb[(long)st1.y * 64 + lane];
        u32 a2 = hb[(long)st2.x * 64 + lane]; u32 r2 = rb[(long)st2.y * 64 + lane];
        u32 a3 = hb[(long)st3.x * 64 + lane]; u32 r3 = rb[(long)st3.y * 64 + lane];
        sx += bf2f((u16)(a0 & 0xffff)) + bf2f((u16)(r0 & 0xffff));
        sy += bf2f((u16)(a0 >> 16))    + bf2f((u16)(r0 >> 16));
        sx += bf2f((u16)(a1 & 0xffff)) + bf2f((u16)(r1 & 0xffff));
        sy += bf2f((u16)(a1 >> 16))    + bf2f((u16)(r1 >> 16));
        sx += bf2f((u16)(a2 & 0xffff)) + bf2f((u16)(r2 & 0xffff));
        sy += bf2f((u16)(a2 >> 16))    + bf2f((u16)(r2 >> 16));
        sx += bf2f((u16)(a3 & 0xffff)) + bf2f((u16)(r3 & 0xffff));
        sy += bf2f((u16)(a3 >> 16))    + bf2f((u16)(r3 >> 16));
    }
    for (; e < s1; ++e) {
        int2 st = spack[e];
        u32 a = hb[(long)st.x * 64 + lane];
        u32 r = rb[(long)st.y * 64 + lane];
        sx += bf2f((u16)(a & 0xffff)) + bf2f((u16)(r & 0xffff));
        sy += bf2f((u16)(a >> 16))    + bf2f((u16)(r >> 16));
    }
    bool has = s1 > s0;
    float nrm = has ? frcp((float)(s1 - s0)) : 0.f;
    u32 hv = hb[(long)i * 64 + lane];
    u32 agg = (u32)f2bf(sx * nrm) | ((u32)f2bf(sy * nrm) << 16);
    long o = (long)i * 192 + lane;
    Acat32[o]       = agg;
    Acat32[o + 64]  = has ? hv : 0u;
    Acat32[o + 128] = has ? 0u : hv;
}

// ---------------------------------------------------------------- co-dispatch: [pre_emb+aligned fused, 313 blocks] | [q_rel->attnq/th1->pred, 16 blocks]
__global__ __launch_bounds__(256) void prealnq_k(
    const u16* __restrict__ acat, const u16* __restrict__ bcat,
    const u16* __restrict__ alb, const float* __restrict__ bal,
    u16* __restrict__ preb, u16* __restrict__ alnb,
    const u16* __restrict__ mapb, const int* __restrict__ trip,
    const u16* __restrict__ atb, const float* __restrict__ bias2,
    const u16* __restrict__ h2b, const float* __restrict__ bh2,
    u16* __restrict__ atq, float* __restrict__ pred, u16* __restrict__ X)
{
    __shared__ u16 lds[4][16][136];    // pl (prealn) / th1l (qt) union
    int tid = threadIdx.x;
    int wave = tid >> 6, lane = tid & 63;
    int ln = lane & 15, q = lane >> 4;
    if (blockIdx.x < 313) {
        // ---- prealn branch: pre = rrelu(acat@Bcat^T) -> aligned = pre@W_align^T + b
        int bm = blockIdx.x * 64 + wave * 16;
        int am = bm + ln; if (am > 19999) am = 19999;
        const u16* Ap = acat + (long)am * 384;
        f4v acc[8] = {};
        for (int kc = 0; kc < 384; kc += 32) {
            bf8v af = *(const bf8v*)(Ap + kc + q*8);
#pragma unroll
            for (int nt = 0; nt < 8; ++nt) {
                bf8v bv = *(const bf8v*)(bcat + (nt*16 + ln)*384 + kc + q*8);
                acc[nt] = __builtin_amdgcn_mfma_f32_16x16x32_bf16(af, bv, acc[nt], 0, 0, 0);
            }
        }
#pragma unroll
        for (int nt = 0; nt < 8; ++nt) {
            int n = nt*16 + ln;
#pragma unroll
            for (int r = 0; r < 4; ++r) {
                int m = bm + q*4 + r;
                float v = acc[nt][r];
                v = (v >= 0.f) ? v : v * RRELU_SLOPE;
                u16 hv = f2bf(v);
                lds[wave][q*4 + r][n] = hv;
                if (m < 20000) preb[(long)m*128 + n] = hv;
            }
        }
        // wave-private staging: no block barrier needed
        f4v acc2[8] = {};
        for (int kc = 0; kc < 128; kc += 32) {
            bf8v af = *(const bf8v*)&lds[wave][ln][kc + q*8];
#pragma unroll
            for (int nt = 0; nt < 8; ++nt) {
                bf8v bv = *(const bf8v*)(alb + (nt*16 + ln)*128 + kc + q*8);
                acc2[nt] = __builtin_amdgcn_mfma_f32_16x16x32_bf16(af, bv, acc2[nt], 0, 0, 0);
            }
        }
#pragma unroll
        for (int nt = 0; nt < 8; ++nt) {
            int n = nt*16 + ln;
            float bv = bal[n];
#pragma unroll
            for (int r = 0; r < 4; ++r) {
                int m = bm + q*4 + r;
                if (m < 20000) alnb[(long)m*128 + n] = f2bf(acc2[nt][r] + bv);
            }
        }
        return;
    }
    // ---- qt branch: q_rel gather -> [attnq | th1] -> pred (+ X tail rows)
    int base = (blockIdx.x - 313) * 64 + wave * 16;
    int ar = trip[(base + ln)*3 + 1];
    const u16* Ap = mapb + ar * 128;
    int rm_[4];
#pragma unroll
    for (int r = 0; r < 4; ++r) rm_[r] = trip[(base + q*4 + r)*3 + 1];
    f4v acc1[16] = {};
    for (int kc = 0; kc < 128; kc += 32) {
        bf8v af = *(const bf8v*)(Ap + kc + q*8);
#pragma unroll
        for (int nt = 0; nt < 16; ++nt) {
            bf8v bv = *(const bf8v*)(atb + (nt*16 + ln)*128 + kc + q*8);
            acc1[nt] = __builtin_amdgcn_mfma_f32_16x16x32_bf16(af, bv, acc1[nt], 0, 0, 0);
        }
    }
#pragma unroll
    for (int nt = 0; nt < 16; ++nt) {
        int n = nt*16 + ln;
        float bv = bias2[n];
#pragma unroll
        for (int r = 0; r < 4; ++r) {
            int m = base + q*4 + r;
            float x = acc1[nt][r] + bv;
            if (nt < 8) {
                atq[m*128 + n] = f2bf(x);
                X[(long)(8192 + m)*128 + n] = mapb[rm_[r]*128 + n];  // X tail = q_rel
            } else lds[wave][q*4 + r][n - 128] = f2bf(x);
        }
    }
    // wave-private staging: no block barrier needed
    f4v acc2[8] = {};
    for (int kc = 0; kc < 128; kc += 32) {
        bf8v af = *(const bf8v*)&lds[wave][ln][kc + q*8];
#pragma unroll
        for (int nt = 0; nt < 8; ++nt) {
            bf8v bv = *(const bf8v*)(h2b + (nt*16 + ln)*128 + kc + q*8);
            acc2[nt] = __builtin_amdgcn_mfma_f32_16x16x32_bf16(af, bv, acc2[nt], 0, 0, 0);
        }
    }
#pragma unroll
    for (int nt = 0; nt < 8; ++nt) {
        int n = nt*16 + ln;
        float bv = bh2[n];
#pragma unroll
        for (int r = 0; r < 4; ++r) {
            int m = base + q*4 + r;
            pred[(long)m*128 + n] = 0.1f * (acc2[nt][r] + bv) + bf2f(mapb[rm_[r]*128 + n]);
        }
    }
}

// ---------------------------------------------------------------- fused A-rows + masked-softmax(460) + rel_path GEMM (K=480)
// block = 4 batch rows x 8 timesteps; A rows computed in-kernel via replicated-row MFMA
__global__ __launch_bounds__(256) void smrp_k(
    const u16* __restrict__ atq, const u16* __restrict__ mapb,
    const float* __restrict__ part, const u16* __restrict__ mapT, u16* __restrict__ X)
{
    __shared__ u16 xls[32][488];
    __shared__ float asl[4][464];
    int tid = threadIdx.x;
    int wave = tid >> 6, lane = tid & 63;
    int ln = lane & 15, q = lane >> 4;
    int b0 = blockIdx.x * 4;           // 256 blocks x 4 batch rows
    // A[db][n] = atq[b0+db] @ mapped_rel^T  (29 n-tiles strided over waves)
    {
        const u16* Ap = atq + (long)(b0 + (ln & 3)) * 128;
        bf8v af[4];
#pragma unroll
        for (int kc = 0; kc < 4; ++kc) af[kc] = *(const bf8v*)(Ap + kc*32 + q*8);
        for (int nt = wave; nt < 29; nt += 4) {
            int brow = nt*16 + ln; if (brow > 459) brow = 459;
            f4v acc = {};
#pragma unroll
            for (int kc = 0; kc < 4; ++kc) {
                bf8v bv = *(const bf8v*)(mapb + (long)brow*128 + kc*32 + q*8);
                acc = __builtin_amdgcn_mfma_f32_16x16x32_bf16(af[kc], bv, acc, 0, 0, 0);
            }
            if (q == 0) {
                int n = nt*16 + ln;
                if (n < 460) {
#pragma unroll
                    for (int r = 0; r < 4; ++r) asl[r][n] = acc[r];
                }
            }
        }
    }
    __syncthreads();
    for (int j = 0; j < 8; ++j) {
        int rl = wave*8 + j;           // rl = t*4 + db
        int t = rl >> 2, db = rl & 3;
        const float* crow = part + (long)(b0 + db)*3680 + t*460;
        float v[8], e[8];
        float m = -1e30f;
#pragma unroll
        for (int i = 0; i < 8; ++i) {
            int r = i*64 + lane;
            if (r < 460) {
                float x = crow[r] * asl[db][r];
                x = (x == 0.f) ? -1e9f : x;
                v[i] = x; m = fmaxf(m, x);
            } else v[i] = -1e30f;
        }
#pragma unroll
        for (int off = 32; off; off >>= 1) m = fmaxf(m, __shfl_xor(m, off));
        float sum = 0.f;
#pragma unroll
        for (int i = 0; i < 8; ++i) {
            int r = i*64 + lane;
            e[i] = 0.f;
            if (r < 460) { e[i] = __expf(v[i] - m); sum += e[i]; }
        }
#pragma unroll
        for (int off = 32; off; off >>= 1) sum += __shfl_xor(sum, off);
        float inv = frcp(sum);
#pragma unroll
        for (int i = 0; i < 8; ++i) {
            int r = i*64 + lane;
            if (r < 460)      xls[rl][r] = f2bf(e[i] * inv);
            else if (r < 488) xls[rl][r] = 0;
        }
    }
    __syncthreads();
    f4v acc[2][2] = {};
    for (int kc = 0; kc < 480; kc += 32) {
        bf8v a[2], bfr[2];
#pragma unroll
        for (int mt = 0; mt < 2; ++mt)
            a[mt] = *(const bf8v*)&xls[mt*16 + ln][kc + q*8];
#pragma unroll
        for (int nt = 0; nt < 2; ++nt)
            bfr[nt] = *(const bf8v*)(mapT + (wave*32 + nt*16 + ln)*480 + kc + q*8);
#pragma unroll
        for (int mt = 0; mt < 2; ++mt)
#pragma unroll
            for (int nt = 0; nt < 2; ++nt)
                acc[mt][nt] = __builtin_amdgcn_mfma_f32_16x16x32_bf16(a[mt], bfr[nt], acc[mt][nt], 0, 0, 0);
    }
#pragma unroll
    for (int mt = 0; mt < 2; ++mt)
#pragma unroll
    for (int nt = 0; nt < 2; ++nt) {
        int n = wave*32 + nt*16 + ln;
#pragma unroll
        for (int r = 0; r < 4; ++r) {
            int rl = mt*16 + q*4 + r;
            long m = (long)(rl >> 2)*1024 + b0 + (rl & 3);
            X[m*128 + n] = f2bf(acc[mt][nt][r]);
        }
    }
}

// ---------------------------------------------------------------- GRU scan: fused gi = X@wih^T, fused SubL prologue, fused V/obj epilogue
__global__ __launch_bounds__(256, 1) void gru_k(
    const u16* __restrict__ X, const u16* __restrict__ wihb, const float* __restrict__ bih,
    const u16* __restrict__ whhb, const float* __restrict__ bhh,
    const float* __restrict__ pred,
    const u16* __restrict__ preb, const u16* __restrict__ alb, const float* __restrict__ bal,
    const u16* __restrict__ AL, const int* __restrict__ trip,
    u16* __restrict__ V, float* __restrict__ accp)
{
    __shared__ u16  hbf[16][136];   // rows 4..15 stay zero
    __shared__ float hf [4][128];
    __shared__ float ghl[4][388];
    __shared__ float gil[4][388];
    __shared__ float sll[4][132];
    __shared__ float redm[4], redo[4];
    int tid = threadIdx.x;
    int wave = tid >> 6, lane = tid & 63;
    int ln = lane & 15, q = lane >> 4;
    int bb = blockIdx.x * 4;
    for (int i = tid; i < 16*136; i += 256) hbf[i/136][i%136] = 0;
    for (int i = tid; i < 4*128; i += 256) hf[i>>7][i&127] = 0.f;
    // preload whh + wih fragments: 6 N-tiles x 4 K-chunks per wave each (192 VGPRs; 1 blk/CU anyway)
    bf8v bfrag[6][4], wfrag[6][4];
#pragma unroll
    for (int nt = 0; nt < 6; ++nt)
#pragma unroll
        for (int kc = 0; kc < 4; ++kc) {
            bfrag[nt][kc] = *(const bf8v*)(whhb + (long)(wave*96 + nt*16 + ln)*128 + kc*32 + q*8);
            wfrag[nt][kc] = *(const bf8v*)(wihb + (long)(wave*96 + nt*16 + ln)*128 + kc*32 + q*8);
        }
    // SubL = pre_emb[trip[:,0]] @ W_align^T + b_align for this block's 4 rows
    {
        const u16* Pp = preb + (long)trip[(bb + (ln & 3))*3 + 0] * 128;
        f4v sacc[2] = {};
#pragma unroll
        for (int kc = 0; kc < 4; ++kc) {
            bf8v pf = *(const bf8v*)(Pp + kc*32 + q*8);
#pragma unroll
            for (int nt = 0; nt < 2; ++nt) {
                bf8v bv = *(const bf8v*)(alb + (long)(wave*32 + nt*16 + ln)*128 + kc*32 + q*8);
                sacc[nt] = __builtin_amdgcn_mfma_f32_16x16x32_bf16(pf, bv, sacc[nt], 0, 0, 0);
            }
        }
        if (q == 0) {
#pragma unroll
            for (int nt = 0; nt < 2; ++nt) {
                int n = wave*32 + nt*16 + ln;
                float bv = bal[n];
#pragma unroll
                for (int r = 0; r < 4; ++r) sll[r][n] = sacc[nt][r] + bv;
            }
        }
    }
    int k = tid & 127;
    float cr = bih[k] + bhh[k];
    float cz = bih[128 + k] + bhh[128 + k];
    float bin_ = bih[256 + k], bhn = bhh[256 + k];
    __syncthreads();
    float msum = 0.f, osum = 0.f;
    for (int t = 0; t <= 8; ++t) {
        float pv[2];
#pragma unroll
        for (int it = 0; it < 2; ++it) {
            int m = it*2 + (tid >> 7);
            pv[it] = (t >= 7) ? pred[(long)(bb + m)*128 + k] : 0.f;
        }
        if (t == 8) {
#pragma unroll
            for (int it = 0; it < 2; ++it) {
                int m = it*2 + (tid >> 7);
                hf[m][k] = pv[it]; hbf[m][k] = f2bf(pv[it]);
            }
            __syncthreads();
        }
        // gi = x_t @ wih^T (rows from X, 4-way replicated across lanes) ; gh = h @ whh^T
        long xr0 = (t < 8) ? ((long)t*1024 + bb) : (long)(8192 + bb);
        const u16* Xp = X + (xr0 + (ln & 3))*128;
        f4v gacc[6] = {};
        f4v acc[6] = {};
#pragma unroll
        for (int kc = 0; kc < 4; ++kc) {
            bf8v xf = *(const bf8v*)(Xp + kc*32 + q*8);
            bf8v af = *(const bf8v*)&hbf[ln][kc*32 + q*8];
#pragma unroll
            for (int nt = 0; nt < 6; ++nt) {
                gacc[nt] = __builtin_amdgcn_mfma_f32_16x16x32_bf16(xf, wfrag[nt][kc], gacc[nt], 0, 0, 0);
                acc[nt]  = __builtin_amdgcn_mfma_f32_16x16x32_bf16(af, bfrag[nt][kc], acc[nt],  0, 0, 0);
            }
        }
        if (q == 0) {
#pragma unroll
            for (int nt = 0; nt < 6; ++nt)
#pragma unroll
                for (int r = 0; r < 4; ++r) {
                    ghl[r][wave*96 + nt*16 + ln] = acc[nt][r];
                    gil[r][wave*96 + nt*16 + ln] = gacc[nt][r];
                }
        }
        __syncthreads();
#pragma unroll
        for (int it = 0; it < 2; ++it) {
            int m = it*2 + (tid >> 7);
            float rr = fsigm(gil[m][k] + ghl[m][k] + cr);
            float zz = fsigm(gil[m][128 + k] + ghl[m][128 + k] + cz);
            float nn = ftanh(gil[m][256 + k] + bin_ + rr * (ghl[m][256 + k] + bhn));
            float hn = (1.f - zz) * nn + zz * hf[m][k];
            if (t == 7) { float d = pv[it] - hn; msum += d*d; }
            if (t == 8) {
                u16 vb = f2bf(sll[m][k] * hn);
                V[(long)(bb + m)*128 + k] = vb;
                int obj = trip[(bb + m)*3 + 2];
                osum += bf2f(vb) * bf2f(AL[(long)obj*128 + k]);
            } else { hf[m][k] = hn; hbf[m][k] = f2bf(hn); }
        }
        __syncthreads();
    }
#pragma unroll
    for (int off = 32; off; off >>= 1) { msum += __shfl_down(msum, off); osum += __shfl_down(osum, off); }
    if (lane == 0) { redm[wave] = msum; redo[wave] = osum; }
    __syncthreads();
    if (tid == 0) {
        atomicAdd(accp + 0, redm[0] + redm[1] + redm[2] + redm[3]);
        atomicAdd(accp + 2, -(redo[0] + redo[1] + redo[2] + redo[3]));
    }
}

// ---------------------------------------------------------------- score GEMM: 8 waves x (64x32)/wave, half-tile LDS staging,
// full-line PLAIN stores (L2 write-back path; nt stores measured ~4x slower than L2 aggregation);
// grid (8,157): consecutive blocks share the AL column strip for L2 reuse.
// e = exp(-|s|), d = 1+e:  sigma = (s>=0 ? 1 : e)/d ;  softplus(s) = max(s,0) + log(d)
__global__ __launch_bounds__(512) void score_k(
    const u16* __restrict__ V, const u16* __restrict__ AL,
    float* __restrict__ out, float* __restrict__ sp_acc, int N)
{
    __shared__ float stage[8][1024];   // 32 rows x 32 cols f32 per wave (wave-private)
    int tid = threadIdx.x;
    int wave = tid >> 6, lane = tid & 63;
    int ln = lane & 15, q = lane >> 4;
    int bm = blockIdx.x * 128 + (wave >> 2) * 64;
    int bn = blockIdx.y * 128 + (wave & 3) * 32;
    bool valid = bn < N;               // N % 32 == 0 -> whole 32-col strip valid or not
    int br[2];
#pragma unroll
    for (int nt = 0; nt < 2; ++nt) { int n = bn + nt*16 + ln; br[nt] = (n < N) ? n : (N - 1); }
    f4v acc[4][2] = {};
    for (int kc = 0; kc < 128; kc += 32) {
        bf8v a[4], b[2];
#pragma unroll
        for (int mt = 0; mt < 4; ++mt)
            a[mt] = *(const bf8v*)(V + (long)(bm + mt*16 + ln)*128 + kc + q*8);
#pragma unroll
        for (int nt = 0; nt < 2; ++nt)
            b[nt] = *(const bf8v*)(AL + (long)br[nt]*128 + kc + q*8);
#pragma unroll
        for (int mt = 0; mt < 4; ++mt)
#pragma unroll
            for (int nt = 0; nt < 2; ++nt)
                acc[mt][nt] = __builtin_amdgcn_mfma_f32_16x16x32_bf16(a[mt], b[nt], acc[mt][nt], 0, 0, 0);
    }
    float lsum = 0.f;
    float* st = stage[wave];
#pragma unroll
    for (int half = 0; half < 2; ++half) {
#pragma unroll
        for (int mh = 0; mh < 2; ++mh) {
            int mt = half*2 + mh;
#pragma unroll
            for (int nt = 0; nt < 2; ++nt)
#pragma unroll
            for (int r = 0; r < 4; ++r) {
                float s = acc[mt][nt][r];
                float e = __expf(-fabsf(s));
                float d = 1.f + e;
                float inv = frcp(d);
                st[(mh*16 + q*4 + r)*32 + nt*16 + ln] = (s >= 0.f) ? inv : e * inv;
                lsum += fmaxf(s, 0.f) + __logf(d);
            }
        }
        // wave-private LDS: no block barrier needed; write full 128B lines via L2 write-back
        if (valid) {
            int row0 = lane >> 3, c4 = (lane & 7) << 2;
#pragma unroll
            for (int i = 0; i < 4; ++i) {
                int row = i*8 + row0;
                f4v vv = *(const f4v*)&st[row*32 + c4];
                *(f4v*)&out[(long)(bm + half*32 + row)*N + bn + c4] = vv;
            }
        }
    }
    if (!valid) lsum = 0.f;
#pragma unroll
    for (int off = 32; off; off >>= 1) lsum += __shfl_xor(lsum, off);
    __shared__ float red[8];
    if (lane == 0) red[wave] = lsum;
    __syncthreads();
    if (tid == 0) {
        float tsum = 0.f;
#pragma unroll
        for (int w = 0; w < 8; ++w) tsum += red[w];
        atomicAdd(sp_acc, tsum);
    }
}

// ---------------------------------------------------------------- finalize scalars
__global__ void final_k(const float* __restrict__ acc, float* __restrict__ out)
{
    out[20480000] = acc[0] / (1024.f * 128.f);
    out[20480001] = (acc[1] + acc[2]) / (1024.f * 20000.f);
}

// ================================================================ host
extern "C" void kernel_launch(void* const* d_in, const int* in_sizes, int n_in,
                              void* d_out, int out_size, void* d_ws, size_t ws_size,
                              hipStream_t stream)
{
    const float* ent  = (const float*)d_in[0];
    const float* rel  = (const float*)d_in[1];
    const float* Wn   = (const float*)d_in[2];
    const float* Wl   = (const float*)d_in[3];
    const float* We   = (const float*)d_in[4];
    const float* wih  = (const float*)d_in[5];
    const float* whh  = (const float*)d_in[6];
    const float* b_ih = (const float*)d_in[7];
    const float* b_hh = (const float*)d_in[8];
    const float* Wm1  = (const float*)d_in[9];
    const float* bm1  = (const float*)d_in[10];
    const float* Wm2  = (const float*)d_in[11];
    const float* bm2  = (const float*)d_in[12];
    const float* Wh1  = (const float*)d_in[13];
    const float* bh1  = (const float*)d_in[14];
    const float* Wh2  = (const float*)d_in[15];
    const float* bh2  = (const float*)d_in[16];
    const float* Wal  = (const float*)d_in[17];
    const float* bal  = (const float*)d_in[18];
    const float* Wat  = (const float*)d_in[19];
    const float* bat  = (const float*)d_in[20];
    const float* part = (const float*)d_in[21];
    const int* esrc   = (const int*)d_in[22];
    const int* edst   = (const int*)d_in[23];
    const int* etyp   = (const int*)d_in[24];
    const int* trip   = (const int*)d_in[25];
    float* out = (float*)d_out;
    const int E = in_sizes[22];

    char* ws = (char*)d_ws;
    size_t off = 0;
    auto alloc = [&](size_t bytes) { size_t o = off; off = (off + bytes + 255) & ~(size_t)255; return o; };

    // zeroed region first (one memset)
    size_t o_acc   = alloc(256);                  // [0]=match [1]=softplus [2]=obj
    size_t o_hist  = alloc(20000 * 4);
    size_t o_mapT  = alloc(128 * 480 * 2);
    size_t zend = off;
    // non-zeroed
    size_t o_starts= alloc(20004 * 4);
    size_t o_cur   = alloc(20000 * 4);
    size_t o_spack = alloc((size_t)E * 8);
    size_t o_entb  = alloc((size_t)20000 * 128 * 2);
    size_t o_acat  = alloc((size_t)20000 * 384 * 2);
    size_t o_pre   = alloc((size_t)20000 * 128 * 2);
    size_t o_aln   = alloc((size_t)20000 * 128 * 2);
    size_t o_bcat  = alloc(128 * 384 * 2);
    size_t o_wih   = alloc(384 * 128 * 2);
    size_t o_whh   = alloc(384 * 128 * 2);
    size_t o_m1    = alloc(256 * 128 * 2);
    size_t o_m2    = alloc(128 * 256 * 2);
    size_t o_ath   = alloc(2 * 128 * 128 * 2);    // [W_attn ; W_h1] adjacent (N=256 stage-1)
    size_t o_h2    = alloc(128 * 128 * 2);
    size_t o_al    = alloc(128 * 128 * 2);
    size_t o_rel   = alloc(460 * 128 * 2);
    size_t o_map   = alloc(460 * 128 * 2);
    size_t o_wcb   = alloc(128 * 128 * 2);        // composed rel-map weight (bf16)
    size_t o_bcf   = alloc(128 * 4);              // composed rel-map bias (f32)
    size_t o_atq   = alloc(1024 * 128 * 2);
    size_t o_b2    = alloc(256 * 4);              // [b_attn ; b_h1]
    size_t o_pred  = alloc(1024 * 128 * 4);
    size_t o_X     = alloc((size_t)9216 * 128 * 2);
    size_t o_V     = alloc(1024 * 128 * 2);

    float* accp  = (float*)(ws + o_acc);
    int* histp   = (int*)(ws + o_hist);
    u16* mapT    = (u16*)(ws + o_mapT);
    int* startsp = (int*)(ws + o_starts);
    int* curp    = (int*)(ws + o_cur);
    int2* spack  = (int2*)(ws + o_spack);
    u16* entb    = (u16*)(ws + o_entb);
    u16* acat    = (u16*)(ws + o_acat);
    u16* preb    = (u16*)(ws + o_pre);
    u16* alnb    = (u16*)(ws + o_aln);
    u16* bcat    = (u16*)(ws + o_bcat);
    u16* wihb    = (u16*)(ws + o_wih);
    u16* whhb    = (u16*)(ws + o_whh);
    u16* m1b     = (u16*)(ws + o_m1);
    u16* m2b     = (u16*)(ws + o_m2);
    u16* atb     = (u16*)(ws + o_ath);
    u16* h1b     = atb + 128 * 128;
    u16* h2b     = (u16*)(ws + o_h2);
    u16* alb     = (u16*)(ws + o_al);
    u16* relb    = (u16*)(ws + o_rel);
    u16* mapb    = (u16*)(ws + o_map);
    u16* wcb     = (u16*)(ws + o_wcb);
    float* bcombf= (float*)(ws + o_bcf);
    u16* atqb    = (u16*)(ws + o_atq);
    float* bias2 = (float*)(ws + o_b2);
    float* predf = (float*)(ws + o_pred);
    u16* Xb      = (u16*)(ws + o_X);
    u16* Vb      = (u16*)(ws + o_V);

    hipMemsetAsync(ws, 0, zend, stream);

    // prep covers: weights (337408) + ent cast (2560000) + bias concat (256)
    //            + Wcomb (16384) + bcomb (128) + edge histogram (E)
    int ptot = 2914176 + E;
    prep_k<<<(ptot + 255) / 256, 256, 0, stream>>>(
        Wn, Wl, We, wih, whh, Wm1, Wm2, Wh1, Wh2, Wat, Wal, rel,
        ent, bat, bh1, bm1, bm2, edst, E,
        bcat, wihb, whhb, m1b, m2b, h1b, h2b, atb, alb, relb,
        entb, bias2, wcb, bcombf, histp);

    scan_k<<<1, 1024, 0, stream>>>(histp, startsp, curp);

    // co-dispatch: scatter (eb blocks) | single-stage rel-map (8 blocks) — zero LDS
    int eb = (E + 255) / 256;
    scmap_k<<<eb + 8, 256, 0, stream>>>(esrc, edst, etyp, curp, spack, E, eb,
                                        relb, wcb, bcombf, mapb, mapT);

    // agg gather only: 5000 blocks x 4 independent waves, minimal footprint
    agg_k<<<5000, 256, 0, stream>>>(spack, startsp, (const u32*)entb, (const u32*)relb, (u32*)acat);

    // co-dispatch: pre_emb+aligned fused (313 blocks) | q_rel->attnq/th1->pred (16 blocks)
    prealnq_k<<<329, 256, 0, stream>>>(acat, bcat, alb, bal, preb, alnb,
                                       mapb, trip, atb, bias2, h2b, bh2, atqb, predf, Xb);

    // A-rows + softmax + rel_path fused -> X rows 0..8191 (bf16)
    smrp_k<<<256, 256, 0, stream>>>(atqb, mapb, part, mapT, Xb);

    // GRU scan with fused gi-GEMM, SubL prologue, V/obj epilogue
    gru_k<<<256, 256, 0, stream>>>(Xb, wihb, b_ih, whhb, b_hh, predf, preb, alb, bal, alnb, trip, Vb, accp);

    // score + softplus reduce  (grid: row-tiles fastest -> AL strip L2 reuse)
    score_k<<<dim3(8, 157), 512, 0, stream>>>(Vb, alnb, out, accp + 1, 20000);

    final_k<<<1, 1, 0, stream>>>(accp, out);

    (void)in_sizes; (void)n_in; (void)out_size; (void)ws_size;
}